// Round 4
// baseline (282.445 us; speedup 1.0000x reference)
//
#include <hip/hip_runtime.h>
#include <hip/hip_bf16.h>

#define BN 4
#define NN 4096
#define DD 128

typedef __attribute__((ext_vector_type(8))) __bf16 bf16x8;
typedef __attribute__((ext_vector_type(4))) float f32x4;

__device__ inline unsigned short f2bf(float f) {
  unsigned int u = __float_as_uint(f);
  unsigned int r = (u + 0x7FFFu + ((u >> 16) & 1u)) >> 16;
  return (unsigned short)r;
}
__device__ inline float bf2f(unsigned short s) {
  return __uint_as_float(((unsigned int)s) << 16);
}

// ---------------- kernel 1: cast x (fp32) -> xb (bf16) ----------------
__global__ __launch_bounds__(256) void k_cvt(const float* __restrict__ x,
                                             unsigned short* __restrict__ xb) {
  int i = (blockIdx.x * 256 + threadIdx.x) * 8;
  float4 a = *(const float4*)(x + i);
  float4 c = *(const float4*)(x + i + 4);
  alignas(16) unsigned short r[8] = {f2bf(a.x), f2bf(a.y), f2bf(a.z), f2bf(a.w),
                                     f2bf(c.x), f2bf(c.y), f2bf(c.z), f2bf(c.w)};
  *(uint4*)(xb + i) = *(const uint4*)r;
}

// ---- kernel 2: colpart[(ic*BN+b)][j] = sum_{i in chunk ic} relu(<x_i,x_j>) ----
__global__ __launch_bounds__(256) void k_colsum(const unsigned short* __restrict__ xb,
                                                float* __restrict__ colpart) {
  __shared__ unsigned short Xj[64 * 128];
  __shared__ unsigned short Xi[64 * 128];
  __shared__ float red[2][64];
  const int b = blockIdx.y, j0 = blockIdx.x * 64, ic = blockIdx.z;
  const int tid = threadIdx.x, lane = tid & 63, w = tid >> 6;
  const unsigned short* xbb = xb + b * NN * DD;

  // j-tile staged once (64 rows x 16 granules of 8 ushort)
  for (int c = tid; c < 1024; c += 256) {
    int row = c >> 4, g = c & 15;
    *(uint4*)&Xj[row * 128 + ((g ^ (row & 7)) << 3)] =
        *(const uint4*)&xbb[(j0 + row) * 128 + g * 8];
  }
  const int wr = w >> 1, wc = w & 1;
  float colacc0 = 0.f, colacc1 = 0.f;

  const int ibeg = ic * (NN / 8), iend = ibeg + (NN / 8);

  // prologue prefetch: i-tile ibeg -> registers
  uint4 st[4];
#pragma unroll
  for (int k = 0; k < 4; ++k) {
    int c = tid + 256 * k;
    int row = c >> 4, g = c & 15;
    st[k] = *(const uint4*)&xbb[(ibeg + row) * 128 + g * 8];
  }

  for (int i0 = ibeg; i0 < iend; i0 += 64) {
    __syncthreads();  // prev compute done reading Xi; Xj staged (iter 0)
#pragma unroll
    for (int k = 0; k < 4; ++k) {
      int c = tid + 256 * k;
      int row = c >> 4, g = c & 15;
      *(uint4*)&Xi[row * 128 + ((g ^ (row & 7)) << 3)] = st[k];
    }
    if (i0 + 64 < iend) {
#pragma unroll
      for (int k = 0; k < 4; ++k) {
        int c = tid + 256 * k;
        int row = c >> 4, g = c & 15;
        st[k] = *(const uint4*)&xbb[(i0 + 64 + row) * 128 + g * 8];
      }
    }
    __syncthreads();

    f32x4 acc00 = {}, acc01 = {}, acc10 = {}, acc11 = {};
#pragma unroll
    for (int kk = 0; kk < 4; ++kk) {
      int g = kk * 4 + (lane >> 4);
      bf16x8 a0, a1, b0, b1;
      { int r = wr * 32 + (lane & 15);      a0 = *(const bf16x8*)&Xi[r * 128 + ((g ^ (r & 7)) << 3)]; }
      { int r = wr * 32 + 16 + (lane & 15); a1 = *(const bf16x8*)&Xi[r * 128 + ((g ^ (r & 7)) << 3)]; }
      { int r = wc * 32 + (lane & 15);      b0 = *(const bf16x8*)&Xj[r * 128 + ((g ^ (r & 7)) << 3)]; }
      { int r = wc * 32 + 16 + (lane & 15); b1 = *(const bf16x8*)&Xj[r * 128 + ((g ^ (r & 7)) << 3)]; }
      acc00 = __builtin_amdgcn_mfma_f32_16x16x32_bf16(a0, b0, acc00, 0, 0, 0);
      acc01 = __builtin_amdgcn_mfma_f32_16x16x32_bf16(a0, b1, acc01, 0, 0, 0);
      acc10 = __builtin_amdgcn_mfma_f32_16x16x32_bf16(a1, b0, acc10, 0, 0, 0);
      acc11 = __builtin_amdgcn_mfma_f32_16x16x32_bf16(a1, b1, acc11, 0, 0, 0);
    }
    {
      float s0 = 0.f, s1 = 0.f;
#pragma unroll
      for (int r = 0; r < 4; ++r) {
        s0 += fmaxf(acc00[r], 0.f) + fmaxf(acc10[r], 0.f);
        s1 += fmaxf(acc01[r], 0.f) + fmaxf(acc11[r], 0.f);
      }
      s0 += __shfl_xor(s0, 16); s0 += __shfl_xor(s0, 32);
      s1 += __shfl_xor(s1, 16); s1 += __shfl_xor(s1, 32);
      colacc0 += s0; colacc1 += s1;
    }
  }
  __syncthreads();
  if (lane < 16) {
    red[wr][wc * 32 + lane] = colacc0;
    red[wr][wc * 32 + 16 + lane] = colacc1;
  }
  __syncthreads();
  if (tid < 64) colpart[(ic * BN + b) * NN + j0 + tid] = red[0][tid] + red[1][tid];
}

// ---- kernel 3: yt[b][d][j] = bf16(x[b][j][d] / sum_ic colpart) ----
__global__ __launch_bounds__(256) void k_ytrans(const float* __restrict__ x,
                                                const float* __restrict__ colpart,
                                                unsigned short* __restrict__ yt) {
  __shared__ unsigned short T[64 * 72];
  const int b = blockIdx.z, j0 = blockIdx.y * 64, d0 = blockIdx.x * 64;
  const int tid = threadIdx.x;
  int jr = tid >> 2, q0 = (tid & 3) * 16;
  float cs = 0.f;
#pragma unroll
  for (int ic = 0; ic < 8; ++ic) cs += colpart[(ic * BN + b) * NN + j0 + jr];
  float inv = 1.0f / cs;
  const float* xr = x + (size_t)(b * NN + j0 + jr) * DD + d0 + q0;
#pragma unroll
  for (int q = 0; q < 4; ++q) {
    float4 v = *(const float4*)(xr + q * 4);
    int dc = q0 + q * 4;
    T[jr * 72 + dc + 0] = f2bf(v.x * inv);
    T[jr * 72 + dc + 1] = f2bf(v.y * inv);
    T[jr * 72 + dc + 2] = f2bf(v.z * inv);
    T[jr * 72 + dc + 3] = f2bf(v.w * inv);
  }
  __syncthreads();
  for (int c = tid; c < 512; c += 256) {
    int dr = c >> 3, jg = c & 7;
    alignas(16) unsigned short tmp[8];
#pragma unroll
    for (int u = 0; u < 8; ++u) tmp[u] = T[(jg * 8 + u) * 72 + dr];
    *(uint4*)&yt[(size_t)(b * DD + d0 + dr) * NN + j0 + jg * 8] = *(const uint4*)tmp;
  }
}

// ---- kernel 4: opart[zc][b*NN+i][:] = sum_{j in chunk zc} relu(<x_i,x_j>) y[j][:] ----
__global__ __launch_bounds__(256) void k_pass2(const unsigned short* __restrict__ xb,
                                               const unsigned short* __restrict__ yt,
                                               unsigned short* __restrict__ opart,
                                               int jc) {
  __shared__ unsigned short Xi[64 * 128];
  __shared__ unsigned short Xj[64 * 128];  // first 8 KB reused as P after S-phase
  __shared__ unsigned short Ys[128 * 64];
  unsigned short* P = Xj;
  const int b = blockIdx.y, i0 = blockIdx.x * 64, zc = blockIdx.z;
  const int tid = threadIdx.x, lane = tid & 63, w = tid >> 6;
  const unsigned short* xbb = xb + b * NN * DD;
  const unsigned short* ytb = yt + (size_t)b * DD * NN;

  // iter split over zc: jc==3 -> [22,21,21] iters of 64; jc==1 -> all 64
  int jbeg, jend;
  if (jc == 1) {
    jbeg = 0; jend = NN;
  } else {
    int si = (zc == 0) ? 0 : (22 + 21 * (zc - 1));
    int ei = si + ((zc == 0) ? 22 : 21);
    jbeg = si * 64; jend = ei * 64;
  }

  for (int c = tid; c < 1024; c += 256) {
    int row = c >> 4, g = c & 15;
    *(uint4*)&Xi[row * 128 + ((g ^ (row & 7)) << 3)] =
        *(const uint4*)&xbb[(i0 + row) * 128 + g * 8];
  }
  const int wr = w >> 1, wc = w & 1;
  f32x4 oacc[8] = {};

  // prologue prefetch: tile jbeg -> registers (Xj: st[0..3], Ys: st[4..7])
  uint4 st[8];
#pragma unroll
  for (int k = 0; k < 4; ++k) {
    int c = tid + 256 * k;
    int row = c >> 4, g = c & 15;
    st[k] = *(const uint4*)&xbb[(jbeg + row) * 128 + g * 8];
  }
#pragma unroll
  for (int k = 0; k < 4; ++k) {
    int cc = tid + 256 * k;
    int dr = cc >> 3, jg = cc & 7;
    st[4 + k] = *(const uint4*)&ytb[(size_t)dr * NN + jbeg + jg * 8];
  }

  for (int j0 = jbeg; j0 < jend; j0 += 64) {
    __syncthreads();  // prev PV done reading P(Xj)/Ys; Xi staged (iter 0)
#pragma unroll
    for (int k = 0; k < 4; ++k) {
      int c = tid + 256 * k;
      int row = c >> 4, g = c & 15;
      *(uint4*)&Xj[row * 128 + ((g ^ (row & 7)) << 3)] = st[k];
    }
#pragma unroll
    for (int k = 0; k < 4; ++k) {
      int cc = tid + 256 * k;
      int dr = cc >> 3, jg = cc & 7;
      *(uint4*)&Ys[dr * 64 + ((jg ^ (dr & 7)) << 3)] = st[4 + k];
    }
    if (j0 + 64 < jend) {
#pragma unroll
      for (int k = 0; k < 4; ++k) {
        int c = tid + 256 * k;
        int row = c >> 4, g = c & 15;
        st[k] = *(const uint4*)&xbb[(j0 + 64 + row) * 128 + g * 8];
      }
#pragma unroll
      for (int k = 0; k < 4; ++k) {
        int cc = tid + 256 * k;
        int dr = cc >> 3, jg = cc & 7;
        st[4 + k] = *(const uint4*)&ytb[(size_t)dr * NN + j0 + 64 + jg * 8];
      }
    }
    __syncthreads();

    f32x4 acc00 = {}, acc01 = {}, acc10 = {}, acc11 = {};
#pragma unroll
    for (int kk = 0; kk < 4; ++kk) {
      int g = kk * 4 + (lane >> 4);
      bf16x8 a0, a1, b0, b1;
      { int r = wr * 32 + (lane & 15);      a0 = *(const bf16x8*)&Xi[r * 128 + ((g ^ (r & 7)) << 3)]; }
      { int r = wr * 32 + 16 + (lane & 15); a1 = *(const bf16x8*)&Xi[r * 128 + ((g ^ (r & 7)) << 3)]; }
      { int r = wc * 32 + (lane & 15);      b0 = *(const bf16x8*)&Xj[r * 128 + ((g ^ (r & 7)) << 3)]; }
      { int r = wc * 32 + 16 + (lane & 15); b1 = *(const bf16x8*)&Xj[r * 128 + ((g ^ (r & 7)) << 3)]; }
      acc00 = __builtin_amdgcn_mfma_f32_16x16x32_bf16(a0, b0, acc00, 0, 0, 0);
      acc01 = __builtin_amdgcn_mfma_f32_16x16x32_bf16(a0, b1, acc01, 0, 0, 0);
      acc10 = __builtin_amdgcn_mfma_f32_16x16x32_bf16(a1, b0, acc10, 0, 0, 0);
      acc11 = __builtin_amdgcn_mfma_f32_16x16x32_bf16(a1, b1, acc11, 0, 0, 0);
    }
    __syncthreads();  // all waves done reading Xj -> safe to overwrite with P
    // relu -> P (bf16, swizzled), exact C layout
#pragma unroll
    for (int m = 0; m < 2; ++m)
#pragma unroll
      for (int n = 0; n < 2; ++n)
#pragma unroll
        for (int r = 0; r < 4; ++r) {
          float v;
          if (m == 0 && n == 0) v = acc00[r];
          else if (m == 0 && n == 1) v = acc01[r];
          else if (m == 1 && n == 0) v = acc10[r];
          else v = acc11[r];
          int row = wr * 32 + m * 16 + (lane >> 4) * 4 + r;
          int col = wc * 32 + n * 16 + (lane & 15);
          P[row * 64 + (((col >> 3) ^ (row & 7)) << 3) + (col & 7)] = f2bf(fmaxf(v, 0.f));
        }
    __syncthreads();
    // out += P @ Y   (wave w owns rows w*16 .. w*16+15, all 128 d columns)
#pragma unroll
    for (int kq = 0; kq < 2; ++kq) {
      int g = kq * 4 + (lane >> 4);
      bf16x8 a;
      { int r = w * 16 + (lane & 15); a = *(const bf16x8*)&P[r * 64 + ((g ^ (r & 7)) << 3)]; }
#pragma unroll
      for (int n = 0; n < 8; ++n) {
        int r = n * 16 + (lane & 15);
        bf16x8 bb = *(const bf16x8*)&Ys[r * 64 + ((g ^ (r & 7)) << 3)];
        oacc[n] = __builtin_amdgcn_mfma_f32_16x16x32_bf16(a, bb, oacc[n], 0, 0, 0);
      }
    }
  }
  // epilogue: oacc (fp32) -> bf16, via LDS (Xi reused, linear) for coalesced stores
  __syncthreads();
#pragma unroll
  for (int n = 0; n < 8; ++n)
#pragma unroll
    for (int r = 0; r < 4; ++r) {
      int row = w * 16 + (lane >> 4) * 4 + r;
      int col = n * 16 + (lane & 15);
      Xi[row * 128 + col] = f2bf(oacc[n][r]);
    }
  __syncthreads();
  for (int c = tid; c < 1024; c += 256) {
    int row = c >> 4, g = c & 15;
    *(uint4*)&opart[((size_t)zc * (BN * NN) + b * NN + i0 + row) * DD + g * 8] =
        *(const uint4*)&Xi[row * 128 + g * 8];
  }
}

// ---- kernel 5: out = tanh((sum_zc opart) @ W^T + bias) + x ----
__global__ __launch_bounds__(256) void k_final(const unsigned short* __restrict__ opart,
                                               int jc,
                                               const float* __restrict__ W,
                                               const float* __restrict__ bias,
                                               const float* __restrict__ x,
                                               float* __restrict__ out) {
  __shared__ float Wt[128 * 128];          // Wt[d][h] = W[h][d]
  __shared__ unsigned short PreS[64 * 128];
  const int tid = threadIdx.x;
  const int r0 = blockIdx.x * 64;
  {
    int h = tid >> 1, k0 = (tid & 1) * 64;
    const float* wr = W + h * 128 + k0;
#pragma unroll
    for (int q = 0; q < 16; ++q) {
      float4 v = *(const float4*)(wr + q * 4);
      Wt[(k0 + q * 4 + 0) * 128 + h] = v.x;
      Wt[(k0 + q * 4 + 1) * 128 + h] = v.y;
      Wt[(k0 + q * 4 + 2) * 128 + h] = v.z;
      Wt[(k0 + q * 4 + 3) * 128 + h] = v.w;
    }
  }
  // stage row sums over jc chunks into PreS (bf16)
  for (int c = tid; c < 1024; c += 256) {
    int row = c >> 4, g = c & 15;
    float s[8] = {0.f, 0.f, 0.f, 0.f, 0.f, 0.f, 0.f, 0.f};
    for (int ch = 0; ch < jc; ++ch) {
      uint4 pk = *(const uint4*)&opart[((size_t)ch * (BN * NN) + r0 + row) * DD + g * 8];
      alignas(16) unsigned short us[8];
      *(uint4*)us = pk;
#pragma unroll
      for (int u = 0; u < 8; ++u) s[u] += bf2f(us[u]);
    }
    alignas(16) unsigned short rs[8];
#pragma unroll
    for (int u = 0; u < 8; ++u) rs[u] = f2bf(s[u]);
    *(uint4*)&PreS[row * 128 + g * 8] = *(const uint4*)rs;
  }
  const int h = tid & 127;
  float bh = bias[h];
  __syncthreads();
  for (int it = 0; it < 32; ++it) {
    int lr = it * 2 + (tid >> 7);
    int ri = r0 + lr;
    float acc = bh;
#pragma unroll
    for (int k8 = 0; k8 < 16; ++k8) {
      uint4 pk = *(const uint4*)&PreS[lr * 128 + k8 * 8];
      alignas(16) unsigned short us[8];
      *(uint4*)us = pk;
#pragma unroll
      for (int u = 0; u < 8; ++u) acc += bf2f(us[u]) * Wt[(k8 * 8 + u) * 128 + h];
    }
    out[(size_t)ri * 128 + h] = tanhf(acc) + x[(size_t)ri * 128 + h];
  }
}

extern "C" void kernel_launch(void* const* d_in, const int* in_sizes, int n_in,
                              void* d_out, int out_size, void* d_ws, size_t ws_size,
                              hipStream_t stream) {
  (void)in_sizes; (void)n_in; (void)out_size;
  const float* x = (const float*)d_in[0];
  const float* W = (const float*)d_in[1];
  const float* bias = (const float*)d_in[2];
  float* out = (float*)d_out;
  char* ws = (char*)d_ws;
  unsigned short* xb = (unsigned short*)ws;                       // 4 MB @ 0
  unsigned short* yt = (unsigned short*)(ws + (4u << 20));        // 4 MB @ 4M
  float* colpart = (float*)(ws + (8u << 20));                     // 512 KB @ 8M
  unsigned short* opart = (unsigned short*)(ws + (9u << 20));     // jc*4 MB @ 9M

  // j-chunk count for pass2: 3 (grid = 768 = exactly 3 blocks/CU) if ws allows
  const size_t need3 = (9u << 20) + 3u * (4u << 20);
  const int jc = (ws_size >= need3) ? 3 : 1;

  k_cvt<<<1024, 256, 0, stream>>>(x, xb);
  k_colsum<<<dim3(64, 4, 8), 256, 0, stream>>>(xb, colpart);
  k_ytrans<<<dim3(2, 64, 4), 256, 0, stream>>>(x, colpart, yt);
  k_pass2<<<dim3(64, 4, jc), 256, 0, stream>>>(xb, yt, opart, jc);
  k_final<<<256, 256, 0, stream>>>(opart, jc, W, bias, x, out);
}

// Round 5
// 278.548 us; speedup vs baseline: 1.0140x; 1.0140x over previous
//
#include <hip/hip_runtime.h>
#include <hip/hip_bf16.h>

#define BN 4
#define NN 4096
#define DD 128

typedef __attribute__((ext_vector_type(8))) __bf16 bf16x8;
typedef __attribute__((ext_vector_type(4))) float f32x4;

__device__ inline unsigned short f2bf(float f) {
  unsigned int u = __float_as_uint(f);
  unsigned int r = (u + 0x7FFFu + ((u >> 16) & 1u)) >> 16;
  return (unsigned short)r;
}
__device__ inline float bf2f(unsigned short s) {
  return __uint_as_float(((unsigned int)s) << 16);
}

// ---------------- kernel 1: cast x (fp32) -> xb (bf16) ----------------
__global__ __launch_bounds__(256) void k_cvt(const float* __restrict__ x,
                                             unsigned short* __restrict__ xb) {
  int i = (blockIdx.x * 256 + threadIdx.x) * 8;
  float4 a = *(const float4*)(x + i);
  float4 c = *(const float4*)(x + i + 4);
  alignas(16) unsigned short r[8] = {f2bf(a.x), f2bf(a.y), f2bf(a.z), f2bf(a.w),
                                     f2bf(c.x), f2bf(c.y), f2bf(c.z), f2bf(c.w)};
  *(uint4*)(xb + i) = *(const uint4*)r;
}

// ---- kernel 2: colpart[(ic*BN+b)][j] = sum_{i in chunk ic} relu(<x_i,x_j>) ----
// __launch_bounds__(256,2): VGPR cap 256 so the prefetch regs do NOT spill
__global__ __launch_bounds__(256, 2) void k_colsum(const unsigned short* __restrict__ xb,
                                                   float* __restrict__ colpart) {
  __shared__ unsigned short Xj[64 * 128];
  __shared__ unsigned short Xi[64 * 128];
  __shared__ float red[2][64];
  const int b = blockIdx.y, j0 = blockIdx.x * 64, ic = blockIdx.z;
  const int tid = threadIdx.x, lane = tid & 63, w = tid >> 6;
  const unsigned short* xbb = xb + b * NN * DD;

  // j-tile staged once (64 rows x 16 granules of 8 ushort)
  for (int c = tid; c < 1024; c += 256) {
    int row = c >> 4, g = c & 15;
    *(uint4*)&Xj[row * 128 + ((g ^ (row & 7)) << 3)] =
        *(const uint4*)&xbb[(j0 + row) * 128 + g * 8];
  }
  const int wr = w >> 1, wc = w & 1;
  float colacc0 = 0.f, colacc1 = 0.f;

  const int ibeg = ic * (NN / 8), iend = ibeg + (NN / 8);

  // prologue prefetch: i-tile ibeg -> registers
  uint4 st[4];
#pragma unroll
  for (int k = 0; k < 4; ++k) {
    int c = tid + 256 * k;
    int row = c >> 4, g = c & 15;
    st[k] = *(const uint4*)&xbb[(ibeg + row) * 128 + g * 8];
  }

  for (int i0 = ibeg; i0 < iend; i0 += 64) {
    __syncthreads();  // prev compute done reading Xi; Xj staged (iter 0)
#pragma unroll
    for (int k = 0; k < 4; ++k) {
      int c = tid + 256 * k;
      int row = c >> 4, g = c & 15;
      *(uint4*)&Xi[row * 128 + ((g ^ (row & 7)) << 3)] = st[k];
    }
    if (i0 + 64 < iend) {
#pragma unroll
      for (int k = 0; k < 4; ++k) {
        int c = tid + 256 * k;
        int row = c >> 4, g = c & 15;
        st[k] = *(const uint4*)&xbb[(i0 + 64 + row) * 128 + g * 8];
      }
    }
    __syncthreads();

    f32x4 acc00 = {}, acc01 = {}, acc10 = {}, acc11 = {};
#pragma unroll
    for (int kk = 0; kk < 4; ++kk) {
      int g = kk * 4 + (lane >> 4);
      bf16x8 a0, a1, b0, b1;
      { int r = wr * 32 + (lane & 15);      a0 = *(const bf16x8*)&Xi[r * 128 + ((g ^ (r & 7)) << 3)]; }
      { int r = wr * 32 + 16 + (lane & 15); a1 = *(const bf16x8*)&Xi[r * 128 + ((g ^ (r & 7)) << 3)]; }
      { int r = wc * 32 + (lane & 15);      b0 = *(const bf16x8*)&Xj[r * 128 + ((g ^ (r & 7)) << 3)]; }
      { int r = wc * 32 + 16 + (lane & 15); b1 = *(const bf16x8*)&Xj[r * 128 + ((g ^ (r & 7)) << 3)]; }
      acc00 = __builtin_amdgcn_mfma_f32_16x16x32_bf16(a0, b0, acc00, 0, 0, 0);
      acc01 = __builtin_amdgcn_mfma_f32_16x16x32_bf16(a0, b1, acc01, 0, 0, 0);
      acc10 = __builtin_amdgcn_mfma_f32_16x16x32_bf16(a1, b0, acc10, 0, 0, 0);
      acc11 = __builtin_amdgcn_mfma_f32_16x16x32_bf16(a1, b1, acc11, 0, 0, 0);
    }
    {
      float s0 = 0.f, s1 = 0.f;
#pragma unroll
      for (int r = 0; r < 4; ++r) {
        s0 += fmaxf(acc00[r], 0.f) + fmaxf(acc10[r], 0.f);
        s1 += fmaxf(acc01[r], 0.f) + fmaxf(acc11[r], 0.f);
      }
      s0 += __shfl_xor(s0, 16); s0 += __shfl_xor(s0, 32);
      s1 += __shfl_xor(s1, 16); s1 += __shfl_xor(s1, 32);
      colacc0 += s0; colacc1 += s1;
    }
  }
  __syncthreads();
  if (lane < 16) {
    red[wr][wc * 32 + lane] = colacc0;
    red[wr][wc * 32 + 16 + lane] = colacc1;
  }
  __syncthreads();
  if (tid < 64) colpart[(ic * BN + b) * NN + j0 + tid] = red[0][tid] + red[1][tid];
}

// ---- kernel 3: yt[b][d][j] = bf16(x[b][j][d] / sum_ic colpart) ----
__global__ __launch_bounds__(256) void k_ytrans(const float* __restrict__ x,
                                                const float* __restrict__ colpart,
                                                unsigned short* __restrict__ yt) {
  __shared__ unsigned short T[64 * 72];
  const int b = blockIdx.z, j0 = blockIdx.y * 64, d0 = blockIdx.x * 64;
  const int tid = threadIdx.x;
  int jr = tid >> 2, q0 = (tid & 3) * 16;
  float cs = 0.f;
#pragma unroll
  for (int ic = 0; ic < 8; ++ic) cs += colpart[(ic * BN + b) * NN + j0 + jr];
  float inv = 1.0f / cs;
  const float* xr = x + (size_t)(b * NN + j0 + jr) * DD + d0 + q0;
#pragma unroll
  for (int q = 0; q < 4; ++q) {
    float4 v = *(const float4*)(xr + q * 4);
    int dc = q0 + q * 4;
    T[jr * 72 + dc + 0] = f2bf(v.x * inv);
    T[jr * 72 + dc + 1] = f2bf(v.y * inv);
    T[jr * 72 + dc + 2] = f2bf(v.z * inv);
    T[jr * 72 + dc + 3] = f2bf(v.w * inv);
  }
  __syncthreads();
  for (int c = tid; c < 512; c += 256) {
    int dr = c >> 3, jg = c & 7;
    alignas(16) unsigned short tmp[8];
#pragma unroll
    for (int u = 0; u < 8; ++u) tmp[u] = T[(jg * 8 + u) * 72 + dr];
    *(uint4*)&yt[(size_t)(b * DD + d0 + dr) * NN + j0 + jg * 8] = *(const uint4*)tmp;
  }
}

// ---- kernel 4: opart[zc][b*NN+i][:] = sum_{j in chunk zc} relu(<x_i,x_j>) y[j][:] ----
// __launch_bounds__(256,2): VGPR cap 256 — st[8]+oacc[8]+acc must stay in regs
__global__ __launch_bounds__(256, 2) void k_pass2(const unsigned short* __restrict__ xb,
                                                  const unsigned short* __restrict__ yt,
                                                  unsigned short* __restrict__ opart,
                                                  int jc) {
  __shared__ unsigned short Xi[64 * 128];
  __shared__ unsigned short Xj[64 * 128];  // first 8 KB reused as P after S-phase
  __shared__ unsigned short Ys[128 * 64];
  unsigned short* P = Xj;
  const int b = blockIdx.y, i0 = blockIdx.x * 64, zc = blockIdx.z;
  const int tid = threadIdx.x, lane = tid & 63, w = tid >> 6;
  const unsigned short* xbb = xb + b * NN * DD;
  const unsigned short* ytb = yt + (size_t)b * DD * NN;

  // iter split over zc: jc==3 -> [22,21,21] iters of 64; jc==1 -> all 64
  int jbeg, jend;
  if (jc == 1) {
    jbeg = 0; jend = NN;
  } else {
    int si = (zc == 0) ? 0 : (22 + 21 * (zc - 1));
    int ei = si + ((zc == 0) ? 22 : 21);
    jbeg = si * 64; jend = ei * 64;
  }

  for (int c = tid; c < 1024; c += 256) {
    int row = c >> 4, g = c & 15;
    *(uint4*)&Xi[row * 128 + ((g ^ (row & 7)) << 3)] =
        *(const uint4*)&xbb[(i0 + row) * 128 + g * 8];
  }
  const int wr = w >> 1, wc = w & 1;
  f32x4 oacc[8] = {};

  // prologue prefetch: tile jbeg -> registers (Xj: st[0..3], Ys: st[4..7])
  uint4 st[8];
#pragma unroll
  for (int k = 0; k < 4; ++k) {
    int c = tid + 256 * k;
    int row = c >> 4, g = c & 15;
    st[k] = *(const uint4*)&xbb[(jbeg + row) * 128 + g * 8];
  }
#pragma unroll
  for (int k = 0; k < 4; ++k) {
    int cc = tid + 256 * k;
    int dr = cc >> 3, jg = cc & 7;
    st[4 + k] = *(const uint4*)&ytb[(size_t)dr * NN + jbeg + jg * 8];
  }

  for (int j0 = jbeg; j0 < jend; j0 += 64) {
    __syncthreads();  // prev PV done reading P(Xj)/Ys; Xi staged (iter 0)
#pragma unroll
    for (int k = 0; k < 4; ++k) {
      int c = tid + 256 * k;
      int row = c >> 4, g = c & 15;
      *(uint4*)&Xj[row * 128 + ((g ^ (row & 7)) << 3)] = st[k];
    }
#pragma unroll
    for (int k = 0; k < 4; ++k) {
      int cc = tid + 256 * k;
      int dr = cc >> 3, jg = cc & 7;
      *(uint4*)&Ys[dr * 64 + ((jg ^ (dr & 7)) << 3)] = st[4 + k];
    }
    if (j0 + 64 < jend) {
#pragma unroll
      for (int k = 0; k < 4; ++k) {
        int c = tid + 256 * k;
        int row = c >> 4, g = c & 15;
        st[k] = *(const uint4*)&xbb[(j0 + 64 + row) * 128 + g * 8];
      }
#pragma unroll
      for (int k = 0; k < 4; ++k) {
        int cc = tid + 256 * k;
        int dr = cc >> 3, jg = cc & 7;
        st[4 + k] = *(const uint4*)&ytb[(size_t)dr * NN + j0 + 64 + jg * 8];
      }
    }
    __syncthreads();

    f32x4 acc00 = {}, acc01 = {}, acc10 = {}, acc11 = {};
#pragma unroll
    for (int kk = 0; kk < 4; ++kk) {
      int g = kk * 4 + (lane >> 4);
      bf16x8 a0, a1, b0, b1;
      { int r = wr * 32 + (lane & 15);      a0 = *(const bf16x8*)&Xi[r * 128 + ((g ^ (r & 7)) << 3)]; }
      { int r = wr * 32 + 16 + (lane & 15); a1 = *(const bf16x8*)&Xi[r * 128 + ((g ^ (r & 7)) << 3)]; }
      { int r = wc * 32 + (lane & 15);      b0 = *(const bf16x8*)&Xj[r * 128 + ((g ^ (r & 7)) << 3)]; }
      { int r = wc * 32 + 16 + (lane & 15); b1 = *(const bf16x8*)&Xj[r * 128 + ((g ^ (r & 7)) << 3)]; }
      acc00 = __builtin_amdgcn_mfma_f32_16x16x32_bf16(a0, b0, acc00, 0, 0, 0);
      acc01 = __builtin_amdgcn_mfma_f32_16x16x32_bf16(a0, b1, acc01, 0, 0, 0);
      acc10 = __builtin_amdgcn_mfma_f32_16x16x32_bf16(a1, b0, acc10, 0, 0, 0);
      acc11 = __builtin_amdgcn_mfma_f32_16x16x32_bf16(a1, b1, acc11, 0, 0, 0);
    }
    __syncthreads();  // all waves done reading Xj -> safe to overwrite with P
    // relu -> P (bf16, swizzled), exact C layout
#pragma unroll
    for (int m = 0; m < 2; ++m)
#pragma unroll
      for (int n = 0; n < 2; ++n)
#pragma unroll
        for (int r = 0; r < 4; ++r) {
          float v;
          if (m == 0 && n == 0) v = acc00[r];
          else if (m == 0 && n == 1) v = acc01[r];
          else if (m == 1 && n == 0) v = acc10[r];
          else v = acc11[r];
          int row = wr * 32 + m * 16 + (lane >> 4) * 4 + r;
          int col = wc * 32 + n * 16 + (lane & 15);
          P[row * 64 + (((col >> 3) ^ (row & 7)) << 3) + (col & 7)] = f2bf(fmaxf(v, 0.f));
        }
    __syncthreads();
    // out += P @ Y   (wave w owns rows w*16 .. w*16+15, all 128 d columns)
#pragma unroll
    for (int kq = 0; kq < 2; ++kq) {
      int g = kq * 4 + (lane >> 4);
      bf16x8 a;
      { int r = w * 16 + (lane & 15); a = *(const bf16x8*)&P[r * 64 + ((g ^ (r & 7)) << 3)]; }
#pragma unroll
      for (int n = 0; n < 8; ++n) {
        int r = n * 16 + (lane & 15);
        bf16x8 bb = *(const bf16x8*)&Ys[r * 64 + ((g ^ (r & 7)) << 3)];
        oacc[n] = __builtin_amdgcn_mfma_f32_16x16x32_bf16(a, bb, oacc[n], 0, 0, 0);
      }
    }
  }
  // epilogue: oacc (fp32) -> bf16, via LDS (Xi reused, linear) for coalesced stores
  __syncthreads();
#pragma unroll
  for (int n = 0; n < 8; ++n)
#pragma unroll
    for (int r = 0; r < 4; ++r) {
      int row = w * 16 + (lane >> 4) * 4 + r;
      int col = n * 16 + (lane & 15);
      Xi[row * 128 + col] = f2bf(oacc[n][r]);
    }
  __syncthreads();
  for (int c = tid; c < 1024; c += 256) {
    int row = c >> 4, g = c & 15;
    *(uint4*)&opart[((size_t)zc * (BN * NN) + b * NN + i0 + row) * DD + g * 8] =
        *(const uint4*)&Xi[row * 128 + g * 8];
  }
}

// ---- kernel 5: out = tanh((sum_zc opart) @ W^T + bias) + x ----
__global__ __launch_bounds__(256) void k_final(const unsigned short* __restrict__ opart,
                                               int jc,
                                               const float* __restrict__ W,
                                               const float* __restrict__ bias,
                                               const float* __restrict__ x,
                                               float* __restrict__ out) {
  __shared__ float Wt[128 * 128];          // Wt[d][h] = W[h][d]
  __shared__ unsigned short PreS[64 * 128];
  const int tid = threadIdx.x;
  const int r0 = blockIdx.x * 64;
  {
    int h = tid >> 1, k0 = (tid & 1) * 64;
    const float* wr = W + h * 128 + k0;
#pragma unroll
    for (int q = 0; q < 16; ++q) {
      float4 v = *(const float4*)(wr + q * 4);
      Wt[(k0 + q * 4 + 0) * 128 + h] = v.x;
      Wt[(k0 + q * 4 + 1) * 128 + h] = v.y;
      Wt[(k0 + q * 4 + 2) * 128 + h] = v.z;
      Wt[(k0 + q * 4 + 3) * 128 + h] = v.w;
    }
  }
  // stage row sums over jc chunks into PreS (bf16)
  for (int c = tid; c < 1024; c += 256) {
    int row = c >> 4, g = c & 15;
    float s[8] = {0.f, 0.f, 0.f, 0.f, 0.f, 0.f, 0.f, 0.f};
    for (int ch = 0; ch < jc; ++ch) {
      uint4 pk = *(const uint4*)&opart[((size_t)ch * (BN * NN) + r0 + row) * DD + g * 8];
      alignas(16) unsigned short us[8];
      *(uint4*)us = pk;
#pragma unroll
      for (int u = 0; u < 8; ++u) s[u] += bf2f(us[u]);
    }
    alignas(16) unsigned short rs[8];
#pragma unroll
    for (int u = 0; u < 8; ++u) rs[u] = f2bf(s[u]);
    *(uint4*)&PreS[row * 128 + g * 8] = *(const uint4*)rs;
  }
  const int h = tid & 127;
  float bh = bias[h];
  __syncthreads();
  for (int it = 0; it < 32; ++it) {
    int lr = it * 2 + (tid >> 7);
    int ri = r0 + lr;
    float acc = bh;
#pragma unroll
    for (int k8 = 0; k8 < 16; ++k8) {
      uint4 pk = *(const uint4*)&PreS[lr * 128 + k8 * 8];
      alignas(16) unsigned short us[8];
      *(uint4*)us = pk;
#pragma unroll
      for (int u = 0; u < 8; ++u) acc += bf2f(us[u]) * Wt[(k8 * 8 + u) * 128 + h];
    }
    out[(size_t)ri * 128 + h] = tanhf(acc) + x[(size_t)ri * 128 + h];
  }
}

extern "C" void kernel_launch(void* const* d_in, const int* in_sizes, int n_in,
                              void* d_out, int out_size, void* d_ws, size_t ws_size,
                              hipStream_t stream) {
  (void)in_sizes; (void)n_in; (void)out_size;
  const float* x = (const float*)d_in[0];
  const float* W = (const float*)d_in[1];
  const float* bias = (const float*)d_in[2];
  float* out = (float*)d_out;
  char* ws = (char*)d_ws;
  unsigned short* xb = (unsigned short*)ws;                       // 4 MB @ 0
  unsigned short* yt = (unsigned short*)(ws + (4u << 20));        // 4 MB @ 4M
  float* colpart = (float*)(ws + (8u << 20));                     // 512 KB @ 8M
  unsigned short* opart = (unsigned short*)(ws + (9u << 20));     // jc*4 MB @ 9M

  // j-chunk count for pass2: 3 (grid = 768 = exactly 3 blocks/CU) if ws allows
  const size_t need3 = (9u << 20) + 3u * (4u << 20);
  const int jc = (ws_size >= need3) ? 3 : 1;

  k_cvt<<<1024, 256, 0, stream>>>(x, xb);
  k_colsum<<<dim3(64, 4, 8), 256, 0, stream>>>(xb, colpart);
  k_ytrans<<<dim3(2, 64, 4), 256, 0, stream>>>(x, colpart, yt);
  k_pass2<<<dim3(64, 4, jc), 256, 0, stream>>>(xb, yt, opart, jc);
  k_final<<<256, 256, 0, stream>>>(opart, jc, W, bias, x, out);
}

// Round 6
// 126.080 us; speedup vs baseline: 2.2402x; 2.2093x over previous
//
#include <hip/hip_runtime.h>
#include <hip/hip_bf16.h>

#define BN 4
#define NN 4096
#define DD 128

typedef __attribute__((ext_vector_type(8))) __bf16 bf16x8;
typedef __attribute__((ext_vector_type(4))) float f32x4;

typedef __attribute__((address_space(1))) const unsigned int* gas_p;
typedef __attribute__((address_space(3))) unsigned int* las_p;

// async DMA: 16 B per lane, LDS dest = uniform base + lane*16 (HW rule)
__device__ __forceinline__ void gload16(const void* g, void* l) {
  __builtin_amdgcn_global_load_lds((gas_p)g, (las_p)l, 16, 0, 0);
}
__device__ __forceinline__ void wait_vm0() {
  asm volatile("s_waitcnt vmcnt(0)" ::: "memory");
}

__device__ inline unsigned short f2bf(float f) {
  unsigned int u = __float_as_uint(f);
  unsigned int r = (u + 0x7FFFu + ((u >> 16) & 1u)) >> 16;
  return (unsigned short)r;
}
__device__ inline float bf2f(unsigned short s) {
  return __uint_as_float(((unsigned int)s) << 16);
}

// ---------------- kernel 1: cast x (fp32) -> xb (bf16) ----------------
__global__ __launch_bounds__(256) void k_cvt(const float* __restrict__ x,
                                             unsigned short* __restrict__ xb) {
  int i = (blockIdx.x * 256 + threadIdx.x) * 8;
  float4 a = *(const float4*)(x + i);
  float4 c = *(const float4*)(x + i + 4);
  alignas(16) unsigned short r[8] = {f2bf(a.x), f2bf(a.y), f2bf(a.z), f2bf(a.w),
                                     f2bf(c.x), f2bf(c.y), f2bf(c.z), f2bf(c.w)};
  *(uint4*)(xb + i) = *(const uint4*)r;
}

// ---- kernel 2: colpart[(ic*BN+b)][j] = sum_{i in chunk ic} relu(<x_i,x_j>) ----
// B-frags (Xj) in regs; Xi double-buffered via global_load_lds (no staging regs)
__global__ __launch_bounds__(256, 2) void k_colsum(const unsigned short* __restrict__ xb,
                                                   float* __restrict__ colpart) {
  __shared__ unsigned short XiB[2][64 * 128];
  __shared__ float red[2][64];
  const int b = blockIdx.y, j0 = blockIdx.x * 64, ic = blockIdx.z;
  const int tid = threadIdx.x, lane = tid & 63, wv = tid >> 6;
  const unsigned short* xbb = xb + b * NN * DD;
  const int wr = wv >> 1, wc = wv & 1;
  const int ibeg = ic * (NN / 8);
  const int nt = (NN / 8) / 64;  // 8

  // prologue: Xj tile -> XiB[0] (linear LDS dest, inverse-swizzled global src)
#pragma unroll
  for (int q = 0; q < 4; ++q) {
    int c = wv * 4 + q;
    int row = (c << 2) + (lane >> 4);
    int gsrc = (lane & 15) ^ (row & 7);
    gload16(&xbb[(j0 + row) * 128 + gsrc * 8], &XiB[0][c * 512]);
  }
  wait_vm0();
  __syncthreads();

  // B-frags to registers (fixed for whole kernel)
  bf16x8 bf0[4], bf1[4];
#pragma unroll
  for (int kk = 0; kk < 4; ++kk) {
    int g = kk * 4 + (lane >> 4);
    { int r = wc * 32 + (lane & 15);      bf0[kk] = *(const bf16x8*)&XiB[0][r * 128 + ((g ^ (r & 7)) << 3)]; }
    { int r = wc * 32 + 16 + (lane & 15); bf1[kk] = *(const bf16x8*)&XiB[0][r * 128 + ((g ^ (r & 7)) << 3)]; }
  }
  // issue tile 0 -> XiB[1]
#pragma unroll
  for (int q = 0; q < 4; ++q) {
    int c = wv * 4 + q;
    int row = (c << 2) + (lane >> 4);
    int gsrc = (lane & 15) ^ (row & 7);
    gload16(&xbb[(ibeg + row) * 128 + gsrc * 8], &XiB[1][c * 512]);
  }

  float colacc0 = 0.f, colacc1 = 0.f;
  for (int t = 0; t < nt; ++t) {
    wait_vm0();
    __syncthreads();  // tile t drained; all waves done with XiB[t&1] (regs read for t=0)
    const int cur = (t + 1) & 1, nxt = t & 1;
    if (t + 1 < nt) {
      const int i1 = ibeg + (t + 1) * 64;
#pragma unroll
      for (int q = 0; q < 4; ++q) {
        int c = wv * 4 + q;
        int row = (c << 2) + (lane >> 4);
        int gsrc = (lane & 15) ^ (row & 7);
        gload16(&xbb[(i1 + row) * 128 + gsrc * 8], &XiB[nxt][c * 512]);
      }
    }
    f32x4 acc00 = {}, acc01 = {}, acc10 = {}, acc11 = {};
#pragma unroll
    for (int kk = 0; kk < 4; ++kk) {
      int g = kk * 4 + (lane >> 4);
      bf16x8 a0, a1;
      { int r = wr * 32 + (lane & 15);      a0 = *(const bf16x8*)&XiB[cur][r * 128 + ((g ^ (r & 7)) << 3)]; }
      { int r = wr * 32 + 16 + (lane & 15); a1 = *(const bf16x8*)&XiB[cur][r * 128 + ((g ^ (r & 7)) << 3)]; }
      acc00 = __builtin_amdgcn_mfma_f32_16x16x32_bf16(a0, bf0[kk], acc00, 0, 0, 0);
      acc01 = __builtin_amdgcn_mfma_f32_16x16x32_bf16(a0, bf1[kk], acc01, 0, 0, 0);
      acc10 = __builtin_amdgcn_mfma_f32_16x16x32_bf16(a1, bf0[kk], acc10, 0, 0, 0);
      acc11 = __builtin_amdgcn_mfma_f32_16x16x32_bf16(a1, bf1[kk], acc11, 0, 0, 0);
    }
    {
      float s0 = 0.f, s1 = 0.f;
#pragma unroll
      for (int r = 0; r < 4; ++r) {
        s0 += fmaxf(acc00[r], 0.f) + fmaxf(acc10[r], 0.f);
        s1 += fmaxf(acc01[r], 0.f) + fmaxf(acc11[r], 0.f);
      }
      s0 += __shfl_xor(s0, 16); s0 += __shfl_xor(s0, 32);
      s1 += __shfl_xor(s1, 16); s1 += __shfl_xor(s1, 32);
      colacc0 += s0; colacc1 += s1;
    }
  }
  __syncthreads();
  if (lane < 16) {
    red[wr][wc * 32 + lane] = colacc0;
    red[wr][wc * 32 + 16 + lane] = colacc1;
  }
  __syncthreads();
  if (tid < 64) colpart[(ic * BN + b) * NN + j0 + tid] = red[0][tid] + red[1][tid];
}

// ---- kernel 3: yt[b][d][j] = bf16(x[b][j][d] / sum_ic colpart) ----
__global__ __launch_bounds__(256) void k_ytrans(const float* __restrict__ x,
                                                const float* __restrict__ colpart,
                                                unsigned short* __restrict__ yt) {
  __shared__ unsigned short T[64 * 72];
  const int b = blockIdx.z, j0 = blockIdx.y * 64, d0 = blockIdx.x * 64;
  const int tid = threadIdx.x;
  int jr = tid >> 2, q0 = (tid & 3) * 16;
  float cs = 0.f;
#pragma unroll
  for (int ic = 0; ic < 8; ++ic) cs += colpart[(ic * BN + b) * NN + j0 + jr];
  float inv = 1.0f / cs;
  const float* xr = x + (size_t)(b * NN + j0 + jr) * DD + d0 + q0;
#pragma unroll
  for (int q = 0; q < 4; ++q) {
    float4 v = *(const float4*)(xr + q * 4);
    int dc = q0 + q * 4;
    T[jr * 72 + dc + 0] = f2bf(v.x * inv);
    T[jr * 72 + dc + 1] = f2bf(v.y * inv);
    T[jr * 72 + dc + 2] = f2bf(v.z * inv);
    T[jr * 72 + dc + 3] = f2bf(v.w * inv);
  }
  __syncthreads();
  for (int c = tid; c < 512; c += 256) {
    int dr = c >> 3, jg = c & 7;
    alignas(16) unsigned short tmp[8];
#pragma unroll
    for (int u = 0; u < 8; ++u) tmp[u] = T[(jg * 8 + u) * 72 + dr];
    *(uint4*)&yt[(size_t)(b * DD + d0 + dr) * NN + j0 + jg * 8] = *(const uint4*)tmp;
  }
}

// ---- kernel 4: opart[zc][b*NN+i][:] = sum_{j in chunk zc} relu(<x_i,x_j>) y[j][:] ----
// A-frags in regs; Xj/Ys double-buffered via global_load_lds; PV split 2x2
__global__ __launch_bounds__(256, 2) void k_pass2(const unsigned short* __restrict__ xb,
                                                  const unsigned short* __restrict__ yt,
                                                  unsigned short* __restrict__ opart,
                                                  int jc) {
  __shared__ unsigned short XjB[2][64 * 128];
  __shared__ unsigned short YsB[2][128 * 64];
  __shared__ unsigned short P[64 * 64];
  const int b = blockIdx.y, i0 = blockIdx.x * 64, zc = blockIdx.z;
  const int tid = threadIdx.x, lane = tid & 63, wv = tid >> 6;
  const unsigned short* xbb = xb + b * NN * DD;
  const unsigned short* ytb = yt + (size_t)b * DD * NN;
  const int wr = wv >> 1, wc = wv & 1;   // S-phase split & PV split (rows, cols)

  const int jspan = NN / jc;
  const int jbeg = zc * jspan;
  const int nt = jspan / 64;

  // prologue: Xi tile -> XjB[0] (for A-frags); tile0 -> XjB[1]/YsB[1]
#pragma unroll
  for (int q = 0; q < 4; ++q) {
    int c = wv * 4 + q;
    int row = (c << 2) + (lane >> 4);
    int gsrc = (lane & 15) ^ (row & 7);
    gload16(&xbb[(i0 + row) * 128 + gsrc * 8], &XjB[0][c * 512]);
  }
#pragma unroll
  for (int q = 0; q < 4; ++q) {
    int c = wv * 4 + q;
    int row = (c << 2) + (lane >> 4);
    int gsrc = (lane & 15) ^ (row & 7);
    gload16(&xbb[(jbeg + row) * 128 + gsrc * 8], &XjB[1][c * 512]);
  }
#pragma unroll
  for (int q = 0; q < 4; ++q) {
    int c = wv * 4 + q;
    int row = (c << 3) + (lane >> 3);
    int gsrc = (lane & 7) ^ (row & 7);
    gload16(&ytb[(size_t)row * NN + jbeg + gsrc * 8], &YsB[1][c * 512]);
  }
  wait_vm0();
  __syncthreads();

  // A-frags (Xi rows wr*32..wr*32+31) to registers — invariant over j
  bf16x8 af0[4], af1[4];
#pragma unroll
  for (int kk = 0; kk < 4; ++kk) {
    int g = kk * 4 + (lane >> 4);
    { int r = wr * 32 + (lane & 15);      af0[kk] = *(const bf16x8*)&XjB[0][r * 128 + ((g ^ (r & 7)) << 3)]; }
    { int r = wr * 32 + 16 + (lane & 15); af1[kk] = *(const bf16x8*)&XjB[0][r * 128 + ((g ^ (r & 7)) << 3)]; }
  }
  f32x4 oacc[8] = {};

  for (int t = 0; t < nt; ++t) {
    wait_vm0();
    __syncthreads();  // tile t drained; prev PV done; A-frag reads done (t=0)
    const int cur = (t + 1) & 1, nxt = t & 1;
    if (t + 1 < nt) {
      const int j1 = jbeg + (t + 1) * 64;
#pragma unroll
      for (int q = 0; q < 4; ++q) {
        int c = wv * 4 + q;
        int row = (c << 2) + (lane >> 4);
        int gsrc = (lane & 15) ^ (row & 7);
        gload16(&xbb[(j1 + row) * 128 + gsrc * 8], &XjB[nxt][c * 512]);
      }
#pragma unroll
      for (int q = 0; q < 4; ++q) {
        int c = wv * 4 + q;
        int row = (c << 3) + (lane >> 3);
        int gsrc = (lane & 7) ^ (row & 7);
        gload16(&ytb[(size_t)row * NN + j1 + gsrc * 8], &YsB[nxt][c * 512]);
      }
    }
    // S = Xi x Xj (A regs, B from XjB[cur])
    f32x4 acc00 = {}, acc01 = {}, acc10 = {}, acc11 = {};
#pragma unroll
    for (int kk = 0; kk < 4; ++kk) {
      int g = kk * 4 + (lane >> 4);
      bf16x8 b0, b1;
      { int r = wc * 32 + (lane & 15);      b0 = *(const bf16x8*)&XjB[cur][r * 128 + ((g ^ (r & 7)) << 3)]; }
      { int r = wc * 32 + 16 + (lane & 15); b1 = *(const bf16x8*)&XjB[cur][r * 128 + ((g ^ (r & 7)) << 3)]; }
      acc00 = __builtin_amdgcn_mfma_f32_16x16x32_bf16(af0[kk], b0, acc00, 0, 0, 0);
      acc01 = __builtin_amdgcn_mfma_f32_16x16x32_bf16(af0[kk], b1, acc01, 0, 0, 0);
      acc10 = __builtin_amdgcn_mfma_f32_16x16x32_bf16(af1[kk], b0, acc10, 0, 0, 0);
      acc11 = __builtin_amdgcn_mfma_f32_16x16x32_bf16(af1[kk], b1, acc11, 0, 0, 0);
    }
    // relu -> P (bf16, swizzled), exact C layout
#pragma unroll
    for (int m = 0; m < 2; ++m)
#pragma unroll
      for (int n = 0; n < 2; ++n)
#pragma unroll
        for (int r = 0; r < 4; ++r) {
          float v;
          if (m == 0 && n == 0) v = acc00[r];
          else if (m == 0 && n == 1) v = acc01[r];
          else if (m == 1 && n == 0) v = acc10[r];
          else v = acc11[r];
          int row = wr * 32 + m * 16 + (lane >> 4) * 4 + r;
          int col = wc * 32 + n * 16 + (lane & 15);
          P[row * 64 + (((col >> 3) ^ (row & 7)) << 3) + (col & 7)] = f2bf(fmaxf(v, 0.f));
        }
    __syncthreads();  // P visible to all waves
    // PV 2x2: wave owns output rows wr*32..+31, cols wc*64..+63
#pragma unroll
    for (int kq = 0; kq < 2; ++kq) {
      int g = kq * 4 + (lane >> 4);
      bf16x8 pa0, pa1;
      { int r = wr * 32 + (lane & 15);      pa0 = *(const bf16x8*)&P[r * 64 + ((g ^ (r & 7)) << 3)]; }
      { int r = wr * 32 + 16 + (lane & 15); pa1 = *(const bf16x8*)&P[r * 64 + ((g ^ (r & 7)) << 3)]; }
#pragma unroll
      for (int n = 0; n < 4; ++n) {
        int r2 = wc * 64 + n * 16 + (lane & 15);
        bf16x8 bb = *(const bf16x8*)&YsB[cur][r2 * 64 + ((g ^ (r2 & 7)) << 3)];
        oacc[0 + n] = __builtin_amdgcn_mfma_f32_16x16x32_bf16(pa0, bb, oacc[0 + n], 0, 0, 0);
        oacc[4 + n] = __builtin_amdgcn_mfma_f32_16x16x32_bf16(pa1, bb, oacc[4 + n], 0, 0, 0);
      }
    }
  }
  // epilogue: oacc -> bf16 via LDS (XjB[0] reused, linear) for coalesced stores
  __syncthreads();
  unsigned short* Sbuf = XjB[0];
#pragma unroll
  for (int m = 0; m < 2; ++m)
#pragma unroll
    for (int n = 0; n < 4; ++n)
#pragma unroll
      for (int r = 0; r < 4; ++r) {
        int row = wr * 32 + m * 16 + (lane >> 4) * 4 + r;
        int col = wc * 64 + n * 16 + (lane & 15);
        Sbuf[row * 128 + col] = f2bf(oacc[m * 4 + n][r]);
      }
  __syncthreads();
  for (int c = tid; c < 1024; c += 256) {
    int row = c >> 4, g = c & 15;
    *(uint4*)&opart[((size_t)zc * (BN * NN) + b * NN + i0 + row) * DD + g * 8] =
        *(const uint4*)&Sbuf[row * 128 + g * 8];
  }
}

// ---- kernel 5: out = tanh((sum_zc opart) @ W^T + bias) + x ----
__global__ __launch_bounds__(256) void k_final(const unsigned short* __restrict__ opart,
                                               int jc,
                                               const float* __restrict__ W,
                                               const float* __restrict__ bias,
                                               const float* __restrict__ x,
                                               float* __restrict__ out) {
  __shared__ float Wt[128 * 128];          // Wt[d][h] = W[h][d]
  __shared__ unsigned short PreS[64 * 128];
  const int tid = threadIdx.x;
  const int r0 = blockIdx.x * 64;
  {
    int h = tid >> 1, k0 = (tid & 1) * 64;
    const float* wr = W + h * 128 + k0;
#pragma unroll
    for (int q = 0; q < 16; ++q) {
      float4 v = *(const float4*)(wr + q * 4);
      Wt[(k0 + q * 4 + 0) * 128 + h] = v.x;
      Wt[(k0 + q * 4 + 1) * 128 + h] = v.y;
      Wt[(k0 + q * 4 + 2) * 128 + h] = v.z;
      Wt[(k0 + q * 4 + 3) * 128 + h] = v.w;
    }
  }
  // stage row sums over jc chunks into PreS (bf16)
  for (int c = tid; c < 1024; c += 256) {
    int row = c >> 4, g = c & 15;
    float s[8] = {0.f, 0.f, 0.f, 0.f, 0.f, 0.f, 0.f, 0.f};
    for (int ch = 0; ch < jc; ++ch) {
      uint4 pk = *(const uint4*)&opart[((size_t)ch * (BN * NN) + r0 + row) * DD + g * 8];
      alignas(16) unsigned short us[8];
      *(uint4*)us = pk;
#pragma unroll
      for (int u = 0; u < 8; ++u) s[u] += bf2f(us[u]);
    }
    alignas(16) unsigned short rs[8];
#pragma unroll
    for (int u = 0; u < 8; ++u) rs[u] = f2bf(s[u]);
    *(uint4*)&PreS[row * 128 + g * 8] = *(const uint4*)rs;
  }
  const int h = tid & 127;
  float bh = bias[h];
  __syncthreads();
  for (int it = 0; it < 32; ++it) {
    int lr = it * 2 + (tid >> 7);
    int ri = r0 + lr;
    float acc = bh;
#pragma unroll
    for (int k8 = 0; k8 < 16; ++k8) {
      uint4 pk = *(const uint4*)&PreS[lr * 128 + k8 * 8];
      alignas(16) unsigned short us[8];
      *(uint4*)us = pk;
#pragma unroll
      for (int u = 0; u < 8; ++u) acc += bf2f(us[u]) * Wt[(k8 * 8 + u) * 128 + h];
    }
    out[(size_t)ri * 128 + h] = tanhf(acc) + x[(size_t)ri * 128 + h];
  }
}

extern "C" void kernel_launch(void* const* d_in, const int* in_sizes, int n_in,
                              void* d_out, int out_size, void* d_ws, size_t ws_size,
                              hipStream_t stream) {
  (void)in_sizes; (void)n_in; (void)out_size;
  const float* x = (const float*)d_in[0];
  const float* W = (const float*)d_in[1];
  const float* bias = (const float*)d_in[2];
  float* out = (float*)d_out;
  char* ws = (char*)d_ws;
  unsigned short* xb = (unsigned short*)ws;                       // 4 MB @ 0
  unsigned short* yt = (unsigned short*)(ws + (4u << 20));        // 4 MB @ 4M
  float* colpart = (float*)(ws + (8u << 20));                     // 512 KB @ 8M
  unsigned short* opart = (unsigned short*)(ws + (9u << 20));     // jc*4 MB @ 9M

  // jc=2: grid 512 = exactly 2 blocks/CU (72 KB LDS), one clean round
  const size_t need2 = (9u << 20) + 2u * (4u << 20);
  const int jc = (ws_size >= need2) ? 2 : 1;

  k_cvt<<<1024, 256, 0, stream>>>(x, xb);
  k_colsum<<<dim3(64, 4, 8), 256, 0, stream>>>(xb, colpart);
  k_ytrans<<<dim3(2, 64, 4), 256, 0, stream>>>(x, colpart, yt);
  k_pass2<<<dim3(64, 4, jc), 256, 0, stream>>>(xb, yt, opart, jc);
  k_final<<<256, 256, 0, stream>>>(opart, jc, W, bias, x, out);
}

// Round 7
// 125.091 us; speedup vs baseline: 2.2579x; 1.0079x over previous
//
#include <hip/hip_runtime.h>
#include <hip/hip_bf16.h>

#define BN 4
#define NN 4096
#define DD 128

typedef __attribute__((ext_vector_type(8))) __bf16 bf16x8;
typedef __attribute__((ext_vector_type(4))) float f32x4;

typedef union {
  bf16x8 v;
  unsigned int u[4];
  uint2 u2[2];
} pk8;

typedef __attribute__((address_space(1))) const unsigned int* gas_p;
typedef __attribute__((address_space(3))) unsigned int* las_p;

__device__ __forceinline__ void gload16(const void* g, void* l) {
  __builtin_amdgcn_global_load_lds((gas_p)g, (las_p)l, 16, 0, 0);
}
__device__ __forceinline__ void wait_vm0() {
  asm volatile("s_waitcnt vmcnt(0)" ::: "memory");
}

__device__ inline unsigned short f2bf(float f) {
  unsigned int u = __float_as_uint(f);
  unsigned int r = (u + 0x7FFFu + ((u >> 16) & 1u)) >> 16;
  return (unsigned short)r;
}
__device__ inline float bf2f(unsigned short s) {
  return __uint_as_float(((unsigned int)s) << 16);
}
// relu both, pack lo|hi<<16
__device__ inline unsigned int pkrelu(float lo, float hi) {
  return (unsigned int)f2bf(fmaxf(lo, 0.f)) | ((unsigned int)f2bf(fmaxf(hi, 0.f)) << 16);
}

// ---------------- kernel 1: cast x (fp32) -> xb (bf16) ----------------
__global__ __launch_bounds__(256) void k_cvt(const float* __restrict__ x,
                                             unsigned short* __restrict__ xb) {
  int i = (blockIdx.x * 256 + threadIdx.x) * 8;
  float4 a = *(const float4*)(x + i);
  float4 c = *(const float4*)(x + i + 4);
  alignas(16) unsigned short r[8] = {f2bf(a.x), f2bf(a.y), f2bf(a.z), f2bf(a.w),
                                     f2bf(c.x), f2bf(c.y), f2bf(c.z), f2bf(c.w)};
  *(uint4*)(xb + i) = *(const uint4*)r;
}

// ---- kernel 2: colpart[(ic*BN+b)][j] = sum_{i in chunk ic} relu(<x_i,x_j>) ----
__global__ __launch_bounds__(256, 2) void k_colsum(const unsigned short* __restrict__ xb,
                                                   float* __restrict__ colpart) {
  __shared__ unsigned short XiB[2][64 * 128];
  __shared__ float red[2][64];
  const int b = blockIdx.y, j0 = blockIdx.x * 64, ic = blockIdx.z;
  const int tid = threadIdx.x, lane = tid & 63, wv = tid >> 6;
  const unsigned short* xbb = xb + b * NN * DD;
  const int wr = wv >> 1, wc = wv & 1;
  const int ibeg = ic * (NN / 8);
  const int nt = (NN / 8) / 64;  // 8

#pragma unroll
  for (int q = 0; q < 4; ++q) {
    int c = wv * 4 + q;
    int row = (c << 2) + (lane >> 4);
    int gsrc = (lane & 15) ^ (row & 7);
    gload16(&xbb[(j0 + row) * 128 + gsrc * 8], &XiB[0][c * 512]);
  }
#pragma unroll
  for (int q = 0; q < 4; ++q) {
    int c = wv * 4 + q;
    int row = (c << 2) + (lane >> 4);
    int gsrc = (lane & 15) ^ (row & 7);
    gload16(&xbb[(ibeg + row) * 128 + gsrc * 8], &XiB[1][c * 512]);
  }
  wait_vm0();
  __syncthreads();

  bf16x8 bf0[4], bf1[4];
#pragma unroll
  for (int kk = 0; kk < 4; ++kk) {
    int g = kk * 4 + (lane >> 4);
    { int r = wc * 32 + (lane & 15);      bf0[kk] = *(const bf16x8*)&XiB[0][r * 128 + ((g ^ (r & 7)) << 3)]; }
    { int r = wc * 32 + 16 + (lane & 15); bf1[kk] = *(const bf16x8*)&XiB[0][r * 128 + ((g ^ (r & 7)) << 3)]; }
  }

  float colacc0 = 0.f, colacc1 = 0.f;
  for (int t = 0; t < nt; ++t) {
    wait_vm0();
    __syncthreads();
    const int cur = (t + 1) & 1, nxt = t & 1;
    if (t + 1 < nt) {
      const int i1 = ibeg + (t + 1) * 64;
#pragma unroll
      for (int q = 0; q < 4; ++q) {
        int c = wv * 4 + q;
        int row = (c << 2) + (lane >> 4);
        int gsrc = (lane & 15) ^ (row & 7);
        gload16(&xbb[(i1 + row) * 128 + gsrc * 8], &XiB[nxt][c * 512]);
      }
    }
    f32x4 acc00 = {}, acc01 = {}, acc10 = {}, acc11 = {};
#pragma unroll
    for (int kk = 0; kk < 4; ++kk) {
      int g = kk * 4 + (lane >> 4);
      bf16x8 a0, a1;
      { int r = wr * 32 + (lane & 15);      a0 = *(const bf16x8*)&XiB[cur][r * 128 + ((g ^ (r & 7)) << 3)]; }
      { int r = wr * 32 + 16 + (lane & 15); a1 = *(const bf16x8*)&XiB[cur][r * 128 + ((g ^ (r & 7)) << 3)]; }
      acc00 = __builtin_amdgcn_mfma_f32_16x16x32_bf16(a0, bf0[kk], acc00, 0, 0, 0);
      acc01 = __builtin_amdgcn_mfma_f32_16x16x32_bf16(a0, bf1[kk], acc01, 0, 0, 0);
      acc10 = __builtin_amdgcn_mfma_f32_16x16x32_bf16(a1, bf0[kk], acc10, 0, 0, 0);
      acc11 = __builtin_amdgcn_mfma_f32_16x16x32_bf16(a1, bf1[kk], acc11, 0, 0, 0);
    }
    {
      float s0 = 0.f, s1 = 0.f;
#pragma unroll
      for (int r = 0; r < 4; ++r) {
        s0 += fmaxf(acc00[r], 0.f) + fmaxf(acc10[r], 0.f);
        s1 += fmaxf(acc01[r], 0.f) + fmaxf(acc11[r], 0.f);
      }
      s0 += __shfl_xor(s0, 16); s0 += __shfl_xor(s0, 32);
      s1 += __shfl_xor(s1, 16); s1 += __shfl_xor(s1, 32);
      colacc0 += s0; colacc1 += s1;
    }
  }
  __syncthreads();
  if (lane < 16) {
    red[wr][wc * 32 + lane] = colacc0;
    red[wr][wc * 32 + 16 + lane] = colacc1;
  }
  __syncthreads();
  if (tid < 64) colpart[(ic * BN + b) * NN + j0 + tid] = red[0][tid] + red[1][tid];
}

// ---- kernel 3: yt[b][d][j] = bf16(x[b][j][d] / sum_ic colpart) ----
__global__ __launch_bounds__(256) void k_ytrans(const float* __restrict__ x,
                                                const float* __restrict__ colpart,
                                                unsigned short* __restrict__ yt) {
  __shared__ unsigned short T[64 * 72];
  const int b = blockIdx.z, j0 = blockIdx.y * 64, d0 = blockIdx.x * 64;
  const int tid = threadIdx.x;
  int jr = tid >> 2, q0 = (tid & 3) * 16;
  float cs = 0.f;
#pragma unroll
  for (int ic = 0; ic < 8; ++ic) cs += colpart[(ic * BN + b) * NN + j0 + jr];
  float inv = 1.0f / cs;
  const float* xr = x + (size_t)(b * NN + j0 + jr) * DD + d0 + q0;
#pragma unroll
  for (int q = 0; q < 4; ++q) {
    float4 v = *(const float4*)(xr + q * 4);
    int dc = q0 + q * 4;
    T[jr * 72 + dc + 0] = f2bf(v.x * inv);
    T[jr * 72 + dc + 1] = f2bf(v.y * inv);
    T[jr * 72 + dc + 2] = f2bf(v.z * inv);
    T[jr * 72 + dc + 3] = f2bf(v.w * inv);
  }
  __syncthreads();
  for (int c = tid; c < 512; c += 256) {
    int dr = c >> 3, jg = c & 7;
    alignas(16) unsigned short tmp[8];
#pragma unroll
    for (int u = 0; u < 8; ++u) tmp[u] = T[(jg * 8 + u) * 72 + dr];
    *(uint4*)&yt[(size_t)(b * DD + d0 + dr) * NN + j0 + jg * 8] = *(const uint4*)tmp;
  }
}

// ---- kernel 4: opart[zc][b*NN+i][:] = sum_{j in chunk zc} relu(<x_i,x_j>) y[j][:] ----
// S^T trick: compute mfma(Xj,Xi) so lane&15 = i; PV k-split by wc makes the
// S->PV handoff wave-local & in-register (no P LDS roundtrip, 1 barrier/iter).
__global__ __launch_bounds__(256, 2) void k_pass2(const unsigned short* __restrict__ xb,
                                                  const unsigned short* __restrict__ yt,
                                                  unsigned short* __restrict__ opart,
                                                  int jc) {
  __shared__ unsigned short XjB[2][64 * 128];  // 32 KB (also f32 sum buffer in epilogue)
  __shared__ unsigned short YsB[2][128 * 64];  // 32 KB (YsB[0] = bf16 staging in epilogue)
  const int b = blockIdx.y, i0 = blockIdx.x * 64, zc = blockIdx.z;
  const int tid = threadIdx.x, lane = tid & 63, wv = tid >> 6;
  const unsigned short* xbb = xb + b * NN * DD;
  const unsigned short* ytb = yt + (size_t)b * DD * NN;
  const int wr = wv >> 1, wc = wv & 1;

  const int jspan = NN / jc;
  const int jbeg = zc * jspan;
  const int nt = jspan / 64;

  // prologue: Xi tile -> XjB[0]; tile0 -> XjB[1]/YsB[1]
#pragma unroll
  for (int q = 0; q < 4; ++q) {
    int c = wv * 4 + q;
    int row = (c << 2) + (lane >> 4);
    int gsrc = (lane & 15) ^ (row & 7);
    gload16(&xbb[(i0 + row) * 128 + gsrc * 8], &XjB[0][c * 512]);
  }
#pragma unroll
  for (int q = 0; q < 4; ++q) {
    int c = wv * 4 + q;
    int row = (c << 2) + (lane >> 4);
    int gsrc = (lane & 15) ^ (row & 7);
    gload16(&xbb[(jbeg + row) * 128 + gsrc * 8], &XjB[1][c * 512]);
  }
#pragma unroll
  for (int q = 0; q < 4; ++q) {
    int c = wv * 4 + q;
    int row = (c << 3) + (lane >> 3);
    int gsrc = (lane & 7) ^ (row & 7);
    gload16(&ytb[(size_t)row * NN + jbeg + gsrc * 8], &YsB[1][c * 512]);
  }
  wait_vm0();
  __syncthreads();

  // Xi B-frags (cols i = wr*32 .. +31), invariant over j
  bf16x8 bf0[4], bf1[4];
#pragma unroll
  for (int kk = 0; kk < 4; ++kk) {
    int g = kk * 4 + (lane >> 4);
    { int r = wr * 32 + (lane & 15);      bf0[kk] = *(const bf16x8*)&XjB[0][r * 128 + ((g ^ (r & 7)) << 3)]; }
    { int r = wr * 32 + 16 + (lane & 15); bf1[kk] = *(const bf16x8*)&XjB[0][r * 128 + ((g ^ (r & 7)) << 3)]; }
  }

  // loop-invariant LDS offsets (ushort units)
  int xjoff[4][2];  // [kk][mj]: S^T A-frag = Xj rows wc*32 + mj*16 + (lane&15)
#pragma unroll
  for (int kk = 0; kk < 4; ++kk) {
    int gd = kk * 4 + (lane >> 4);
#pragma unroll
    for (int mj = 0; mj < 2; ++mj) {
      int r = wc * 32 + mj * 16 + (lane & 15);
      xjoff[kk][mj] = r * 128 + ((gd ^ (r & 7)) << 3);
    }
  }
  int ysoff[8][2];  // [n][h]: PV B b64 reads, custom k-map j = h*16 + g*4 + e
  {
    int g = lane >> 4;
#pragma unroll
    for (int n = 0; n < 8; ++n) {
      int d = n * 16 + (lane & 15);
#pragma unroll
      for (int h = 0; h < 2; ++h) {
        int jq = wc * 4 + 2 * h + (g >> 1);
        ysoff[n][h] = d * 64 + ((jq ^ (d & 7)) << 3) + (g & 1) * 4;
      }
    }
  }

  f32x4 oc0[8] = {}, oc1[8] = {};  // partial PV (k = wc half), rows m=0/1

  for (int t = 0; t < nt; ++t) {
    wait_vm0();
    __syncthreads();
    const int cur = (t + 1) & 1, nxt = t & 1;
    if (t + 1 < nt) {
      const int j1 = jbeg + (t + 1) * 64;
#pragma unroll
      for (int q = 0; q < 4; ++q) {
        int c = wv * 4 + q;
        int row = (c << 2) + (lane >> 4);
        int gsrc = (lane & 15) ^ (row & 7);
        gload16(&xbb[(j1 + row) * 128 + gsrc * 8], &XjB[nxt][c * 512]);
      }
#pragma unroll
      for (int q = 0; q < 4; ++q) {
        int c = wv * 4 + q;
        int row = (c << 3) + (lane >> 3);
        int gsrc = (lane & 7) ^ (row & 7);
        gload16(&ytb[(size_t)row * NN + j1 + gsrc * 8], &YsB[nxt][c * 512]);
      }
    }
    const unsigned short* Xj = XjB[cur];
    const unsigned short* Ys = YsB[cur];

    // S^T: rows j (wc half), cols i (wr half). a{mj}{ni}
    f32x4 a00 = {}, a01 = {}, a10 = {}, a11 = {};
#pragma unroll
    for (int kk = 0; kk < 4; ++kk) {
      bf16x8 aj0 = *(const bf16x8*)&Xj[xjoff[kk][0]];
      bf16x8 aj1 = *(const bf16x8*)&Xj[xjoff[kk][1]];
      a00 = __builtin_amdgcn_mfma_f32_16x16x32_bf16(aj0, bf0[kk], a00, 0, 0, 0);
      a01 = __builtin_amdgcn_mfma_f32_16x16x32_bf16(aj0, bf1[kk], a01, 0, 0, 0);
      a10 = __builtin_amdgcn_mfma_f32_16x16x32_bf16(aj1, bf0[kk], a10, 0, 0, 0);
      a11 = __builtin_amdgcn_mfma_f32_16x16x32_bf16(aj1, bf1[kk], a11, 0, 0, 0);
    }
    // in-register relu + bf16 pack -> PV A-frags (k-map: e<4 -> j=g*4+e ; e>=4 -> j=16+g*4+(e-4))
    pk8 p0, p1;
    p0.u[0] = pkrelu(a00[0], a00[1]); p0.u[1] = pkrelu(a00[2], a00[3]);
    p0.u[2] = pkrelu(a10[0], a10[1]); p0.u[3] = pkrelu(a10[2], a10[3]);
    p1.u[0] = pkrelu(a01[0], a01[1]); p1.u[1] = pkrelu(a01[2], a01[3]);
    p1.u[2] = pkrelu(a11[0], a11[1]); p1.u[3] = pkrelu(a11[2], a11[3]);
    // PV: out rows (wr half, m=ni), all 128 d, k = this wave's 32 j
#pragma unroll
    for (int n = 0; n < 8; ++n) {
      pk8 bb;
      bb.u2[0] = *(const uint2*)&Ys[ysoff[n][0]];
      bb.u2[1] = *(const uint2*)&Ys[ysoff[n][1]];
      oc0[n] = __builtin_amdgcn_mfma_f32_16x16x32_bf16(p0.v, bb.v, oc0[n], 0, 0, 0);
      oc1[n] = __builtin_amdgcn_mfma_f32_16x16x32_bf16(p1.v, bb.v, oc1[n], 0, 0, 0);
    }
  }

  // epilogue: sum wc-partials, cast bf16, coalesced store
  __syncthreads();
  float* fb = (float*)&XjB[0][0];  // 64x128 f32 = 32 KB
  if (wc == 1) {
#pragma unroll
    for (int m = 0; m < 2; ++m)
#pragma unroll
      for (int n = 0; n < 8; ++n)
#pragma unroll
        for (int r = 0; r < 4; ++r) {
          int row = wr * 32 + m * 16 + (lane >> 4) * 4 + r;
          int col = n * 16 + (lane & 15);
          fb[row * 128 + col] = (m == 0 ? oc0[n][r] : oc1[n][r]);
        }
  }
  __syncthreads();
  unsigned short* sb = (unsigned short*)&YsB[0][0];  // 64x128 bf16 = 16 KB
  if (wc == 0) {
#pragma unroll
    for (int m = 0; m < 2; ++m)
#pragma unroll
      for (int n = 0; n < 8; ++n)
#pragma unroll
        for (int r = 0; r < 4; ++r) {
          int row = wr * 32 + m * 16 + (lane >> 4) * 4 + r;
          int col = n * 16 + (lane & 15);
          float v = (m == 0 ? oc0[n][r] : oc1[n][r]) + fb[row * 128 + col];
          sb[row * 128 + col] = f2bf(v);
        }
  }
  __syncthreads();
  for (int c = tid; c < 1024; c += 256) {
    int row = c >> 4, g = c & 15;
    *(uint4*)&opart[((size_t)zc * (BN * NN) + b * NN + i0 + row) * DD + g * 8] =
        *(const uint4*)&sb[row * 128 + g * 8];
  }
}

// ---- kernel 5: out = tanh((sum_zc opart) @ W^T + bias) + x ----
__global__ __launch_bounds__(256) void k_final(const unsigned short* __restrict__ opart,
                                               int jc,
                                               const float* __restrict__ W,
                                               const float* __restrict__ bias,
                                               const float* __restrict__ x,
                                               float* __restrict__ out) {
  __shared__ float Wt[128 * 128];
  __shared__ unsigned short PreS[64 * 128];
  const int tid = threadIdx.x;
  const int r0 = blockIdx.x * 64;
  {
    int h = tid >> 1, k0 = (tid & 1) * 64;
    const float* wr = W + h * 128 + k0;
#pragma unroll
    for (int q = 0; q < 16; ++q) {
      float4 v = *(const float4*)(wr + q * 4);
      Wt[(k0 + q * 4 + 0) * 128 + h] = v.x;
      Wt[(k0 + q * 4 + 1) * 128 + h] = v.y;
      Wt[(k0 + q * 4 + 2) * 128 + h] = v.z;
      Wt[(k0 + q * 4 + 3) * 128 + h] = v.w;
    }
  }
  for (int c = tid; c < 1024; c += 256) {
    int row = c >> 4, g = c & 15;
    float s[8] = {0.f, 0.f, 0.f, 0.f, 0.f, 0.f, 0.f, 0.f};
    for (int ch = 0; ch < jc; ++ch) {
      uint4 pk = *(const uint4*)&opart[((size_t)ch * (BN * NN) + r0 + row) * DD + g * 8];
      alignas(16) unsigned short us[8];
      *(uint4*)us = pk;
#pragma unroll
      for (int u = 0; u < 8; ++u) s[u] += bf2f(us[u]);
    }
    alignas(16) unsigned short rs[8];
#pragma unroll
    for (int u = 0; u < 8; ++u) rs[u] = f2bf(s[u]);
    *(uint4*)&PreS[row * 128 + g * 8] = *(const uint4*)rs;
  }
  const int h = tid & 127;
  float bh = bias[h];
  __syncthreads();
  for (int it = 0; it < 32; ++it) {
    int lr = it * 2 + (tid >> 7);
    int ri = r0 + lr;
    float acc = bh;
#pragma unroll
    for (int k8 = 0; k8 < 16; ++k8) {
      uint4 pk = *(const uint4*)&PreS[lr * 128 + k8 * 8];
      alignas(16) unsigned short us[8];
      *(uint4*)us = pk;
#pragma unroll
      for (int u = 0; u < 8; ++u) acc += bf2f(us[u]) * Wt[(k8 * 8 + u) * 128 + h];
    }
    out[(size_t)ri * 128 + h] = tanhf(acc) + x[(size_t)ri * 128 + h];
  }
}

extern "C" void kernel_launch(void* const* d_in, const int* in_sizes, int n_in,
                              void* d_out, int out_size, void* d_ws, size_t ws_size,
                              hipStream_t stream) {
  (void)in_sizes; (void)n_in; (void)out_size;
  const float* x = (const float*)d_in[0];
  const float* W = (const float*)d_in[1];
  const float* bias = (const float*)d_in[2];
  float* out = (float*)d_out;
  char* ws = (char*)d_ws;
  unsigned short* xb = (unsigned short*)ws;                       // 4 MB @ 0
  unsigned short* yt = (unsigned short*)(ws + (4u << 20));        // 4 MB @ 4M
  float* colpart = (float*)(ws + (8u << 20));                     // 512 KB @ 8M
  unsigned short* opart = (unsigned short*)(ws + (9u << 20));     // jc*4 MB @ 9M

  const size_t need2 = (9u << 20) + 2u * (4u << 20);
  const int jc = (ws_size >= need2) ? 2 : 1;

  k_cvt<<<1024, 256, 0, stream>>>(x, xb);
  k_colsum<<<dim3(64, 4, 8), 256, 0, stream>>>(xb, colpart);
  k_ytrans<<<dim3(2, 64, 4), 256, 0, stream>>>(x, colpart, yt);
  k_pass2<<<dim3(64, 4, jc), 256, 0, stream>>>(xb, yt, opart, jc);
  k_final<<<256, 256, 0, stream>>>(opart, jc, W, bias, x, out);
}

// Round 8
// 122.038 us; speedup vs baseline: 2.3144x; 1.0250x over previous
//
#include <hip/hip_runtime.h>
#include <hip/hip_bf16.h>

#define BN 4
#define NN 4096
#define DD 128

typedef __attribute__((ext_vector_type(8))) __bf16 bf16x8;
typedef __attribute__((ext_vector_type(4))) float f32x4;

typedef union {
  bf16x8 v;
  unsigned int u[4];
  uint2 u2[2];
} pk8;

typedef __attribute__((address_space(1))) const unsigned int* gas_p;
typedef __attribute__((address_space(3))) unsigned int* las_p;

__device__ __forceinline__ void gload16(const void* g, void* l) {
  __builtin_amdgcn_global_load_lds((gas_p)g, (las_p)l, 16, 0, 0);
}
__device__ __forceinline__ void wait_vm0() {
  asm volatile("s_waitcnt vmcnt(0)" ::: "memory");
}
// HW packed f32x2 -> bf16x2 (RNE), 1 VALU op
__device__ __forceinline__ unsigned int cvtpk(float lo, float hi) {
  unsigned int r;
  asm("v_cvt_pk_bf16_f32 %0, %1, %2" : "=v"(r) : "v"(lo), "v"(hi));
  return r;
}
__device__ __forceinline__ unsigned int pkrelu(float lo, float hi) {
  return cvtpk(fmaxf(lo, 0.f), fmaxf(hi, 0.f));
}

__device__ inline unsigned short f2bf(float f) {
  unsigned int u = __float_as_uint(f);
  unsigned int r = (u + 0x7FFFu + ((u >> 16) & 1u)) >> 16;
  return (unsigned short)r;
}
__device__ inline float bf2f(unsigned short s) {
  return __uint_as_float(((unsigned int)s) << 16);
}

// ---------------- kernel 1: cast x (fp32) -> xb (bf16) ----------------
__global__ __launch_bounds__(256) void k_cvt(const float* __restrict__ x,
                                             unsigned short* __restrict__ xb) {
  int i = (blockIdx.x * 256 + threadIdx.x) * 8;
  float4 a = *(const float4*)(x + i);
  float4 c = *(const float4*)(x + i + 4);
  uint4 o;
  o.x = cvtpk(a.x, a.y);
  o.y = cvtpk(a.z, a.w);
  o.z = cvtpk(c.x, c.y);
  o.w = cvtpk(c.z, c.w);
  *(uint4*)(xb + i) = o;
}

// ---- kernel 2: colpart[(ic*BN+b)][j] = sum_{i in chunk ic} relu(<x_i,x_j>) ----
__global__ __launch_bounds__(256, 2) void k_colsum(const unsigned short* __restrict__ xb,
                                                   float* __restrict__ colpart) {
  __shared__ unsigned short XiB[2][64 * 128];
  __shared__ float red[2][64];
  const int b = blockIdx.y, j0 = blockIdx.x * 64, ic = blockIdx.z;
  const int tid = threadIdx.x, lane = tid & 63, wv = tid >> 6;
  const unsigned short* xbb = xb + b * NN * DD;
  const int wr = wv >> 1, wc = wv & 1;
  const int ibeg = ic * (NN / 8);
  const int nt = (NN / 8) / 64;  // 8

#pragma unroll
  for (int q = 0; q < 4; ++q) {
    int c = wv * 4 + q;
    int row = (c << 2) + (lane >> 4);
    int gsrc = (lane & 15) ^ (row & 7);
    gload16(&xbb[(j0 + row) * 128 + gsrc * 8], &XiB[0][c * 512]);
  }
#pragma unroll
  for (int q = 0; q < 4; ++q) {
    int c = wv * 4 + q;
    int row = (c << 2) + (lane >> 4);
    int gsrc = (lane & 15) ^ (row & 7);
    gload16(&xbb[(ibeg + row) * 128 + gsrc * 8], &XiB[1][c * 512]);
  }
  wait_vm0();
  __syncthreads();

  bf16x8 bf0[4], bf1[4];
#pragma unroll
  for (int kk = 0; kk < 4; ++kk) {
    int g = kk * 4 + (lane >> 4);
    { int r = wc * 32 + (lane & 15);      bf0[kk] = *(const bf16x8*)&XiB[0][r * 128 + ((g ^ (r & 7)) << 3)]; }
    { int r = wc * 32 + 16 + (lane & 15); bf1[kk] = *(const bf16x8*)&XiB[0][r * 128 + ((g ^ (r & 7)) << 3)]; }
  }

  float colacc0 = 0.f, colacc1 = 0.f;
  for (int t = 0; t < nt; ++t) {
    wait_vm0();
    __syncthreads();
    const int cur = (t + 1) & 1, nxt = t & 1;
    if (t + 1 < nt) {
      const int i1 = ibeg + (t + 1) * 64;
#pragma unroll
      for (int q = 0; q < 4; ++q) {
        int c = wv * 4 + q;
        int row = (c << 2) + (lane >> 4);
        int gsrc = (lane & 15) ^ (row & 7);
        gload16(&xbb[(i1 + row) * 128 + gsrc * 8], &XiB[nxt][c * 512]);
      }
    }
    f32x4 acc00 = {}, acc01 = {}, acc10 = {}, acc11 = {};
    __builtin_amdgcn_s_setprio(1);
#pragma unroll
    for (int kk = 0; kk < 4; ++kk) {
      int g = kk * 4 + (lane >> 4);
      bf16x8 a0, a1;
      { int r = wr * 32 + (lane & 15);      a0 = *(const bf16x8*)&XiB[cur][r * 128 + ((g ^ (r & 7)) << 3)]; }
      { int r = wr * 32 + 16 + (lane & 15); a1 = *(const bf16x8*)&XiB[cur][r * 128 + ((g ^ (r & 7)) << 3)]; }
      acc00 = __builtin_amdgcn_mfma_f32_16x16x32_bf16(a0, bf0[kk], acc00, 0, 0, 0);
      acc01 = __builtin_amdgcn_mfma_f32_16x16x32_bf16(a0, bf1[kk], acc01, 0, 0, 0);
      acc10 = __builtin_amdgcn_mfma_f32_16x16x32_bf16(a1, bf0[kk], acc10, 0, 0, 0);
      acc11 = __builtin_amdgcn_mfma_f32_16x16x32_bf16(a1, bf1[kk], acc11, 0, 0, 0);
    }
    __builtin_amdgcn_s_setprio(0);
    {
      float s0 = 0.f, s1 = 0.f;
#pragma unroll
      for (int r = 0; r < 4; ++r) {
        s0 += fmaxf(acc00[r], 0.f) + fmaxf(acc10[r], 0.f);
        s1 += fmaxf(acc01[r], 0.f) + fmaxf(acc11[r], 0.f);
      }
      s0 += __shfl_xor(s0, 16); s0 += __shfl_xor(s0, 32);
      s1 += __shfl_xor(s1, 16); s1 += __shfl_xor(s1, 32);
      colacc0 += s0; colacc1 += s1;
    }
  }
  __syncthreads();
  if (lane < 16) {
    red[wr][wc * 32 + lane] = colacc0;
    red[wr][wc * 32 + 16 + lane] = colacc1;
  }
  __syncthreads();
  if (tid < 64) colpart[(ic * BN + b) * NN + j0 + tid] = red[0][tid] + red[1][tid];
}

// ---- kernel 3: yt[b][d][j] = bf16(x[b][j][d] / sum_ic colpart) ----
__global__ __launch_bounds__(256) void k_ytrans(const float* __restrict__ x,
                                                const float* __restrict__ colpart,
                                                unsigned short* __restrict__ yt) {
  __shared__ unsigned short T[64 * 72];
  const int b = blockIdx.z, j0 = blockIdx.y * 64, d0 = blockIdx.x * 64;
  const int tid = threadIdx.x;
  int jr = tid >> 2, q0 = (tid & 3) * 16;
  float cs = 0.f;
#pragma unroll
  for (int ic = 0; ic < 8; ++ic) cs += colpart[(ic * BN + b) * NN + j0 + jr];
  float inv = 1.0f / cs;
  const float* xr = x + (size_t)(b * NN + j0 + jr) * DD + d0 + q0;
#pragma unroll
  for (int q = 0; q < 4; ++q) {
    float4 v = *(const float4*)(xr + q * 4);
    int dc = q0 + q * 4;
    T[jr * 72 + dc + 0] = f2bf(v.x * inv);
    T[jr * 72 + dc + 1] = f2bf(v.y * inv);
    T[jr * 72 + dc + 2] = f2bf(v.z * inv);
    T[jr * 72 + dc + 3] = f2bf(v.w * inv);
  }
  __syncthreads();
  for (int c = tid; c < 512; c += 256) {
    int dr = c >> 3, jg = c & 7;
    alignas(16) unsigned short tmp[8];
#pragma unroll
    for (int u = 0; u < 8; ++u) tmp[u] = T[(jg * 8 + u) * 72 + dr];
    *(uint4*)&yt[(size_t)(b * DD + d0 + dr) * NN + j0 + jg * 8] = *(const uint4*)tmp;
  }
}

// ---- kernel 4: opart[zc][b*NN+i][:] = sum_{j in chunk zc} relu(<x_i,x_j>) y[j][:] ----
// S^T trick: mfma(Xj,Xi) puts i in lane&15; PV k-split by wc keeps the S->PV
// handoff in-register; pack via v_cvt_pk_bf16_f32 (1 op per f32-pair).
__global__ __launch_bounds__(256, 2) void k_pass2(const unsigned short* __restrict__ xb,
                                                  const unsigned short* __restrict__ yt,
                                                  unsigned short* __restrict__ opart,
                                                  int jc) {
  __shared__ unsigned short XjB[2][64 * 128];
  __shared__ unsigned short YsB[2][128 * 64];
  const int b = blockIdx.y, i0 = blockIdx.x * 64, zc = blockIdx.z;
  const int tid = threadIdx.x, lane = tid & 63, wv = tid >> 6;
  const unsigned short* xbb = xb + b * NN * DD;
  const unsigned short* ytb = yt + (size_t)b * DD * NN;
  const int wr = wv >> 1, wc = wv & 1;

  const int jspan = NN / jc;
  const int jbeg = zc * jspan;
  const int nt = jspan / 64;

#pragma unroll
  for (int q = 0; q < 4; ++q) {
    int c = wv * 4 + q;
    int row = (c << 2) + (lane >> 4);
    int gsrc = (lane & 15) ^ (row & 7);
    gload16(&xbb[(i0 + row) * 128 + gsrc * 8], &XjB[0][c * 512]);
  }
#pragma unroll
  for (int q = 0; q < 4; ++q) {
    int c = wv * 4 + q;
    int row = (c << 2) + (lane >> 4);
    int gsrc = (lane & 15) ^ (row & 7);
    gload16(&xbb[(jbeg + row) * 128 + gsrc * 8], &XjB[1][c * 512]);
  }
#pragma unroll
  for (int q = 0; q < 4; ++q) {
    int c = wv * 4 + q;
    int row = (c << 3) + (lane >> 3);
    int gsrc = (lane & 7) ^ (row & 7);
    gload16(&ytb[(size_t)row * NN + jbeg + gsrc * 8], &YsB[1][c * 512]);
  }
  wait_vm0();
  __syncthreads();

  // Xi B-frags (cols i = wr*32 .. +31), invariant over j
  bf16x8 bf0[4], bf1[4];
#pragma unroll
  for (int kk = 0; kk < 4; ++kk) {
    int g = kk * 4 + (lane >> 4);
    { int r = wr * 32 + (lane & 15);      bf0[kk] = *(const bf16x8*)&XjB[0][r * 128 + ((g ^ (r & 7)) << 3)]; }
    { int r = wr * 32 + 16 + (lane & 15); bf1[kk] = *(const bf16x8*)&XjB[0][r * 128 + ((g ^ (r & 7)) << 3)]; }
  }

  int xjoff[4][2];
#pragma unroll
  for (int kk = 0; kk < 4; ++kk) {
    int gd = kk * 4 + (lane >> 4);
#pragma unroll
    for (int mj = 0; mj < 2; ++mj) {
      int r = wc * 32 + mj * 16 + (lane & 15);
      xjoff[kk][mj] = r * 128 + ((gd ^ (r & 7)) << 3);
    }
  }
  int ysoff[8][2];
  {
    int g = lane >> 4;
#pragma unroll
    for (int n = 0; n < 8; ++n) {
      int d = n * 16 + (lane & 15);
#pragma unroll
      for (int h = 0; h < 2; ++h) {
        int jq = wc * 4 + 2 * h + (g >> 1);
        ysoff[n][h] = d * 64 + ((jq ^ (d & 7)) << 3) + (g & 1) * 4;
      }
    }
  }

  f32x4 oc0[8] = {}, oc1[8] = {};

  for (int t = 0; t < nt; ++t) {
    wait_vm0();
    __syncthreads();
    const int cur = (t + 1) & 1, nxt = t & 1;
    if (t + 1 < nt) {
      const int j1 = jbeg + (t + 1) * 64;
#pragma unroll
      for (int q = 0; q < 4; ++q) {
        int c = wv * 4 + q;
        int row = (c << 2) + (lane >> 4);
        int gsrc = (lane & 15) ^ (row & 7);
        gload16(&xbb[(j1 + row) * 128 + gsrc * 8], &XjB[nxt][c * 512]);
      }
#pragma unroll
      for (int q = 0; q < 4; ++q) {
        int c = wv * 4 + q;
        int row = (c << 3) + (lane >> 3);
        int gsrc = (lane & 7) ^ (row & 7);
        gload16(&ytb[(size_t)row * NN + j1 + gsrc * 8], &YsB[nxt][c * 512]);
      }
    }
    const unsigned short* Xj = XjB[cur];
    const unsigned short* Ys = YsB[cur];

    f32x4 a00 = {}, a01 = {}, a10 = {}, a11 = {};
    __builtin_amdgcn_s_setprio(1);
#pragma unroll
    for (int kk = 0; kk < 4; ++kk) {
      bf16x8 aj0 = *(const bf16x8*)&Xj[xjoff[kk][0]];
      bf16x8 aj1 = *(const bf16x8*)&Xj[xjoff[kk][1]];
      a00 = __builtin_amdgcn_mfma_f32_16x16x32_bf16(aj0, bf0[kk], a00, 0, 0, 0);
      a01 = __builtin_amdgcn_mfma_f32_16x16x32_bf16(aj0, bf1[kk], a01, 0, 0, 0);
      a10 = __builtin_amdgcn_mfma_f32_16x16x32_bf16(aj1, bf0[kk], a10, 0, 0, 0);
      a11 = __builtin_amdgcn_mfma_f32_16x16x32_bf16(aj1, bf1[kk], a11, 0, 0, 0);
    }
    __builtin_amdgcn_s_setprio(0);
    // relu + pack via cvt_pk (k-map: e<4 -> j=g*4+e ; e>=4 -> j=16+g*4+(e-4))
    pk8 p0, p1;
    p0.u[0] = pkrelu(a00[0], a00[1]); p0.u[1] = pkrelu(a00[2], a00[3]);
    p0.u[2] = pkrelu(a10[0], a10[1]); p0.u[3] = pkrelu(a10[2], a10[3]);
    p1.u[0] = pkrelu(a01[0], a01[1]); p1.u[1] = pkrelu(a01[2], a01[3]);
    p1.u[2] = pkrelu(a11[0], a11[1]); p1.u[3] = pkrelu(a11[2], a11[3]);
    __builtin_amdgcn_s_setprio(1);
#pragma unroll
    for (int n = 0; n < 8; ++n) {
      pk8 bb;
      bb.u2[0] = *(const uint2*)&Ys[ysoff[n][0]];
      bb.u2[1] = *(const uint2*)&Ys[ysoff[n][1]];
      oc0[n] = __builtin_amdgcn_mfma_f32_16x16x32_bf16(p0.v, bb.v, oc0[n], 0, 0, 0);
      oc1[n] = __builtin_amdgcn_mfma_f32_16x16x32_bf16(p1.v, bb.v, oc1[n], 0, 0, 0);
    }
    __builtin_amdgcn_s_setprio(0);
  }

  // epilogue: sum wc-partials, cast bf16, coalesced store
  __syncthreads();
  float* fb = (float*)&XjB[0][0];
  if (wc == 1) {
#pragma unroll
    for (int m = 0; m < 2; ++m)
#pragma unroll
      for (int n = 0; n < 8; ++n)
#pragma unroll
        for (int r = 0; r < 4; ++r) {
          int row = wr * 32 + m * 16 + (lane >> 4) * 4 + r;
          int col = n * 16 + (lane & 15);
          fb[row * 128 + col] = (m == 0 ? oc0[n][r] : oc1[n][r]);
        }
  }
  __syncthreads();
  unsigned short* sb = (unsigned short*)&YsB[0][0];
  if (wc == 0) {
#pragma unroll
    for (int m = 0; m < 2; ++m)
#pragma unroll
      for (int n = 0; n < 8; ++n)
#pragma unroll
        for (int r = 0; r < 4; ++r) {
          int row = wr * 32 + m * 16 + (lane >> 4) * 4 + r;
          int col = n * 16 + (lane & 15);
          float v = (m == 0 ? oc0[n][r] : oc1[n][r]) + fb[row * 128 + col];
          sb[row * 128 + col] = f2bf(v);
        }
  }
  __syncthreads();
  for (int c = tid; c < 1024; c += 256) {
    int row = c >> 4, g = c & 15;
    *(uint4*)&opart[((size_t)zc * (BN * NN) + b * NN + i0 + row) * DD + g * 8] =
        *(const uint4*)&sb[row * 128 + g * 8];
  }
}

// ---- kernel 5: out = tanh((sum_zc opart) @ W^T + bias) + x ----
__global__ __launch_bounds__(256) void k_final(const unsigned short* __restrict__ opart,
                                               int jc,
                                               const float* __restrict__ W,
                                               const float* __restrict__ bias,
                                               const float* __restrict__ x,
                                               float* __restrict__ out) {
  __shared__ float Wt[128 * 128];
  __shared__ unsigned short PreS[64 * 128];
  const int tid = threadIdx.x;
  const int r0 = blockIdx.x * 64;
  {
    int h = tid >> 1, k0 = (tid & 1) * 64;
    const float* wr = W + h * 128 + k0;
#pragma unroll
    for (int q = 0; q < 16; ++q) {
      float4 v = *(const float4*)(wr + q * 4);
      Wt[(k0 + q * 4 + 0) * 128 + h] = v.x;
      Wt[(k0 + q * 4 + 1) * 128 + h] = v.y;
      Wt[(k0 + q * 4 + 2) * 128 + h] = v.z;
      Wt[(k0 + q * 4 + 3) * 128 + h] = v.w;
    }
  }
  for (int c = tid; c < 1024; c += 256) {
    int row = c >> 4, g = c & 15;
    float s[8] = {0.f, 0.f, 0.f, 0.f, 0.f, 0.f, 0.f, 0.f};
    for (int ch = 0; ch < jc; ++ch) {
      uint4 pk = *(const uint4*)&opart[((size_t)ch * (BN * NN) + r0 + row) * DD + g * 8];
      alignas(16) unsigned short us[8];
      *(uint4*)us = pk;
#pragma unroll
      for (int u = 0; u < 8; ++u) s[u] += bf2f(us[u]);
    }
    alignas(16) unsigned short rs[8];
#pragma unroll
    for (int u = 0; u < 8; ++u) rs[u] = f2bf(s[u]);
    *(uint4*)&PreS[row * 128 + g * 8] = *(const uint4*)rs;
  }
  const int h = tid & 127;
  float bh = bias[h];
  __syncthreads();
  for (int it = 0; it < 32; ++it) {
    int lr = it * 2 + (tid >> 7);
    int ri = r0 + lr;
    float acc = bh;
#pragma unroll
    for (int k8 = 0; k8 < 16; ++k8) {
      uint4 pk = *(const uint4*)&PreS[lr * 128 + k8 * 8];
      alignas(16) unsigned short us[8];
      *(uint4*)us = pk;
#pragma unroll
      for (int u = 0; u < 8; ++u) acc += bf2f(us[u]) * Wt[(k8 * 8 + u) * 128 + h];
    }
    out[(size_t)ri * 128 + h] = tanhf(acc) + x[(size_t)ri * 128 + h];
  }
}

extern "C" void kernel_launch(void* const* d_in, const int* in_sizes, int n_in,
                              void* d_out, int out_size, void* d_ws, size_t ws_size,
                              hipStream_t stream) {
  (void)in_sizes; (void)n_in; (void)out_size;
  const float* x = (const float*)d_in[0];
  const float* W = (const float*)d_in[1];
  const float* bias = (const float*)d_in[2];
  float* out = (float*)d_out;
  char* ws = (char*)d_ws;
  unsigned short* xb = (unsigned short*)ws;                       // 4 MB @ 0
  unsigned short* yt = (unsigned short*)(ws + (4u << 20));        // 4 MB @ 4M
  float* colpart = (float*)(ws + (8u << 20));                     // 512 KB @ 8M
  unsigned short* opart = (unsigned short*)(ws + (9u << 20));     // jc*4 MB @ 9M

  const size_t need2 = (9u << 20) + 2u * (4u << 20);
  const int jc = (ws_size >= need2) ? 2 : 1;

  k_cvt<<<1024, 256, 0, stream>>>(x, xb);
  k_colsum<<<dim3(64, 4, 8), 256, 0, stream>>>(xb, colpart);
  k_ytrans<<<dim3(2, 64, 4), 256, 0, stream>>>(x, colpart, yt);
  k_pass2<<<dim3(64, 4, jc), 256, 0, stream>>>(xb, yt, opart, jc);
  k_final<<<256, 256, 0, stream>>>(opart, jc, W, bias, x, out);
}

// Round 9
// 113.528 us; speedup vs baseline: 2.4879x; 1.0750x over previous
//
#include <hip/hip_runtime.h>
#include <hip/hip_bf16.h>

#define BN 4
#define NN 4096
#define DD 128

typedef __attribute__((ext_vector_type(8))) __bf16 bf16x8;
typedef __attribute__((ext_vector_type(4))) float f32x4;

typedef union {
  bf16x8 v;
  unsigned int u[4];
  uint2 u2[2];
} pk8;

typedef __attribute__((address_space(1))) const unsigned int* gas_p;
typedef __attribute__((address_space(3))) unsigned int* las_p;

__device__ __forceinline__ void gload16(const void* g, void* l) {
  __builtin_amdgcn_global_load_lds((gas_p)g, (las_p)l, 16, 0, 0);
}
__device__ __forceinline__ void wait_vm0() {
  asm volatile("s_waitcnt vmcnt(0)" ::: "memory");
}
__device__ __forceinline__ unsigned int cvtpk(float lo, float hi) {
  unsigned int r;
  asm("v_cvt_pk_bf16_f32 %0, %1, %2" : "=v"(r) : "v"(lo), "v"(hi));
  return r;
}
__device__ __forceinline__ unsigned int pkrelu(float lo, float hi) {
  return cvtpk(fmaxf(lo, 0.f), fmaxf(hi, 0.f));
}

__device__ inline unsigned short f2bf(float f) {
  unsigned int u = __float_as_uint(f);
  unsigned int r = (u + 0x7FFFu + ((u >> 16) & 1u)) >> 16;
  return (unsigned short)r;
}
__device__ inline float bf2f(unsigned short s) {
  return __uint_as_float(((unsigned int)s) << 16);
}

// ---------------- kernel 1: cast x (fp32) -> xb (bf16) ----------------
__global__ __launch_bounds__(256) void k_cvt(const float* __restrict__ x,
                                             unsigned short* __restrict__ xb) {
  int i = (blockIdx.x * 256 + threadIdx.x) * 8;
  float4 a = *(const float4*)(x + i);
  float4 c = *(const float4*)(x + i + 4);
  uint4 o;
  o.x = cvtpk(a.x, a.y);
  o.y = cvtpk(a.z, a.w);
  o.z = cvtpk(c.x, c.y);
  o.w = cvtpk(c.z, c.w);
  *(uint4*)(xb + i) = o;
}

// ---- kernel 2: colpart[(ic*BN+b)][j] = sum_{i in chunk ic} relu(<x_i,x_j>) ----
// j-tile 128 (4 waves x 32 j each, B-frags in regs, no cross-wave reduction);
// Xi streamed 64 rows/iter, double-buffered via global_load_lds.
__global__ __launch_bounds__(256, 4) void k_colsum(const unsigned short* __restrict__ xb,
                                                   float* __restrict__ colpart) {
  __shared__ unsigned short XiB[2][64 * 128];  // 32 KB
  const int b = blockIdx.y, j0 = blockIdx.x * 128, ic = blockIdx.z;
  const int tid = threadIdx.x, lane = tid & 63, wv = tid >> 6;
  const unsigned short* xbb = xb + b * NN * DD;
  const int g = lane >> 4;
  const int ibeg = ic * (NN / 8);
  const int nt = (NN / 8) / 64;  // 8

  // stage Xj 128 rows -> XiB[0] (rows 0-63) and XiB[1] (rows 64-127)
#pragma unroll
  for (int hb = 0; hb < 2; ++hb)
#pragma unroll
    for (int q = 0; q < 4; ++q) {
      int c = wv * 4 + q;
      int lr = c * 4 + g;
      int gsrc = (lane & 15) ^ (lr & 7);
      gload16(&xbb[(j0 + hb * 64 + lr) * 128 + gsrc * 8], &XiB[hb][c * 512]);
    }
  wait_vm0();
  __syncthreads();

  // B-frags: this wave's 32 j = wv*32 + ni*16 + (lane&15)
  bf16x8 bfr[2][4];
#pragma unroll
  for (int ni = 0; ni < 2; ++ni)
#pragma unroll
    for (int kk = 0; kk < 4; ++kk) {
      int lr = (wv & 1) * 32 + ni * 16 + (lane & 15);
      bfr[ni][kk] = *(const bf16x8*)&XiB[wv >> 1][lr * 128 + (((kk * 4 + g) ^ (lr & 7)) << 3)];
    }
  __syncthreads();  // all frags read; XiB free for streaming

  // issue i-tile 0 -> XiB[1]
#pragma unroll
  for (int q = 0; q < 4; ++q) {
    int c = wv * 4 + q;
    int lr = c * 4 + g;
    int gsrc = (lane & 15) ^ (lr & 7);
    gload16(&xbb[(ibeg + lr) * 128 + gsrc * 8], &XiB[1][c * 512]);
  }

  // loop-invariant A-frag base offsets (i-row = lane&15 within 16-block)
  int basek[4];
#pragma unroll
  for (int kk = 0; kk < 4; ++kk)
    basek[kk] = (lane & 15) * 128 + (((kk * 4 + g) ^ (lane & 7)) << 3);

  float colacc0 = 0.f, colacc1 = 0.f;
  for (int t = 0; t < nt; ++t) {
    wait_vm0();
    __syncthreads();
    const int cur = (t + 1) & 1, nxt = t & 1;
    if (t + 1 < nt) {
      const int i1 = ibeg + (t + 1) * 64;
#pragma unroll
      for (int q = 0; q < 4; ++q) {
        int c = wv * 4 + q;
        int lr = c * 4 + g;
        int gsrc = (lane & 15) ^ (lr & 7);
        gload16(&xbb[(i1 + lr) * 128 + gsrc * 8], &XiB[nxt][c * 512]);
      }
    }
    f32x4 a0[4], a1[4];  // [mj] x ni   (C row = i = mj*16+g*4+r, col = j 16-block ni)
#pragma unroll
    for (int mj = 0; mj < 4; ++mj) { a0[mj] = (f32x4){}; a1[mj] = (f32x4){}; }
    __builtin_amdgcn_s_setprio(1);
#pragma unroll
    for (int kk = 0; kk < 4; ++kk) {
      bf16x8 ar0 = *(const bf16x8*)&XiB[cur][basek[kk]];
      bf16x8 ar1 = *(const bf16x8*)&XiB[cur][basek[kk] + 1 * 2048];
      bf16x8 ar2 = *(const bf16x8*)&XiB[cur][basek[kk] + 2 * 2048];
      bf16x8 ar3 = *(const bf16x8*)&XiB[cur][basek[kk] + 3 * 2048];
      a0[0] = __builtin_amdgcn_mfma_f32_16x16x32_bf16(ar0, bfr[0][kk], a0[0], 0, 0, 0);
      a1[0] = __builtin_amdgcn_mfma_f32_16x16x32_bf16(ar0, bfr[1][kk], a1[0], 0, 0, 0);
      a0[1] = __builtin_amdgcn_mfma_f32_16x16x32_bf16(ar1, bfr[0][kk], a0[1], 0, 0, 0);
      a1[1] = __builtin_amdgcn_mfma_f32_16x16x32_bf16(ar1, bfr[1][kk], a1[1], 0, 0, 0);
      a0[2] = __builtin_amdgcn_mfma_f32_16x16x32_bf16(ar2, bfr[0][kk], a0[2], 0, 0, 0);
      a1[2] = __builtin_amdgcn_mfma_f32_16x16x32_bf16(ar2, bfr[1][kk], a1[2], 0, 0, 0);
      a0[3] = __builtin_amdgcn_mfma_f32_16x16x32_bf16(ar3, bfr[0][kk], a0[3], 0, 0, 0);
      a1[3] = __builtin_amdgcn_mfma_f32_16x16x32_bf16(ar3, bfr[1][kk], a1[3], 0, 0, 0);
    }
    __builtin_amdgcn_s_setprio(0);
    {
      float s0 = 0.f, s1 = 0.f;
#pragma unroll
      for (int mj = 0; mj < 4; ++mj)
#pragma unroll
        for (int r = 0; r < 4; ++r) {
          s0 += fmaxf(a0[mj][r], 0.f);
          s1 += fmaxf(a1[mj][r], 0.f);
        }
      s0 += __shfl_xor(s0, 16); s0 += __shfl_xor(s0, 32);
      s1 += __shfl_xor(s1, 16); s1 += __shfl_xor(s1, 32);
      colacc0 += s0; colacc1 += s1;
    }
  }
  if (lane < 16) {
    colpart[(ic * BN + b) * NN + j0 + wv * 32 + lane] = colacc0;
    colpart[(ic * BN + b) * NN + j0 + wv * 32 + 16 + lane] = colacc1;
  }
}

// ---- kernel 3: yt[b][d][j] = bf16(x[b][j][d] / sum_ic colpart) ----
__global__ __launch_bounds__(256) void k_ytrans(const float* __restrict__ x,
                                                const float* __restrict__ colpart,
                                                unsigned short* __restrict__ yt) {
  __shared__ unsigned short T[64 * 72];
  const int b = blockIdx.z, j0 = blockIdx.y * 64, d0 = blockIdx.x * 64;
  const int tid = threadIdx.x;
  int jr = tid >> 2, q0 = (tid & 3) * 16;
  float cs = 0.f;
#pragma unroll
  for (int ic = 0; ic < 8; ++ic) cs += colpart[(ic * BN + b) * NN + j0 + jr];
  float inv = 1.0f / cs;
  const float* xr = x + (size_t)(b * NN + j0 + jr) * DD + d0 + q0;
#pragma unroll
  for (int q = 0; q < 4; ++q) {
    float4 v = *(const float4*)(xr + q * 4);
    int dc = q0 + q * 4;
    T[jr * 72 + dc + 0] = f2bf(v.x * inv);
    T[jr * 72 + dc + 1] = f2bf(v.y * inv);
    T[jr * 72 + dc + 2] = f2bf(v.z * inv);
    T[jr * 72 + dc + 3] = f2bf(v.w * inv);
  }
  __syncthreads();
  for (int c = tid; c < 512; c += 256) {
    int dr = c >> 3, jg = c & 7;
    alignas(16) unsigned short tmp[8];
#pragma unroll
    for (int u = 0; u < 8; ++u) tmp[u] = T[(jg * 8 + u) * 72 + dr];
    *(uint4*)&yt[(size_t)(b * DD + d0 + dr) * NN + j0 + jg * 8] = *(const uint4*)tmp;
  }
}

// ---- kernel 4: opart[zc][b*NN+i][:] = sum_{j in chunk zc} relu(<x_i,x_j>) y[j][:] ----
// BM=128: each wave owns 32 i rows end-to-end (S^T lane&15=i; full k per wave;
// no partial-sum epilogue). Xj/Ys double-buffered via global_load_lds.
__global__ __launch_bounds__(256, 2) void k_pass2(const unsigned short* __restrict__ xb,
                                                  const unsigned short* __restrict__ yt,
                                                  unsigned short* __restrict__ opart,
                                                  int jc) {
  __shared__ unsigned short XjB[2][64 * 128];  // 32 KB (Xi halves in prologue; epilogue sb)
  __shared__ unsigned short YsB[2][128 * 64];  // 32 KB
  const int b = blockIdx.y, i0 = blockIdx.x * 128, zc = blockIdx.z;
  const int tid = threadIdx.x, lane = tid & 63, wv = tid >> 6;
  const unsigned short* xbb = xb + b * NN * DD;
  const unsigned short* ytb = yt + (size_t)b * DD * NN;
  const int g = lane >> 4;

  const int jspan = NN / jc;
  const int jbeg = zc * jspan;
  const int nt = jspan / 64;

  // stage Xi 128 rows -> XjB[0] + XjB[1]; Ys tile0 -> YsB[1]
#pragma unroll
  for (int hb = 0; hb < 2; ++hb)
#pragma unroll
    for (int q = 0; q < 4; ++q) {
      int c = wv * 4 + q;
      int lr = c * 4 + g;
      int gsrc = (lane & 15) ^ (lr & 7);
      gload16(&xbb[(i0 + hb * 64 + lr) * 128 + gsrc * 8], &XjB[hb][c * 512]);
    }
#pragma unroll
  for (int q = 0; q < 4; ++q) {
    int c = wv * 4 + q;
    int dr = c * 8 + (lane >> 3);
    int gsrc = (lane & 7) ^ (dr & 7);
    gload16(&ytb[(size_t)dr * NN + jbeg + gsrc * 8], &YsB[1][c * 512]);
  }
  wait_vm0();
  __syncthreads();

  // Xi B-frags: wave's 32 i = wv*32 + ni*16 + (lane&15)
  bf16x8 bfr[2][4];
#pragma unroll
  for (int ni = 0; ni < 2; ++ni)
#pragma unroll
    for (int kk = 0; kk < 4; ++kk) {
      int lr = (wv & 1) * 32 + ni * 16 + (lane & 15);
      bfr[ni][kk] = *(const bf16x8*)&XjB[wv >> 1][lr * 128 + (((kk * 4 + g) ^ (lr & 7)) << 3)];
    }
  __syncthreads();  // XjB free

  // issue Xj tile0 -> XjB[1]
#pragma unroll
  for (int q = 0; q < 4; ++q) {
    int c = wv * 4 + q;
    int lr = c * 4 + g;
    int gsrc = (lane & 15) ^ (lr & 7);
    gload16(&xbb[(jbeg + lr) * 128 + gsrc * 8], &XjB[1][c * 512]);
  }

  // loop-invariant bases
  int xjb[4];  // S^T A-frag: j-row = mj*16 + (lane&15) -> + mj*2048
#pragma unroll
  for (int kk = 0; kk < 4; ++kk)
    xjb[kk] = (lane & 15) * 128 + (((kk * 4 + g) ^ (lane & 7)) << 3);
  int ysb[2][2];  // PV B b64: d = lane&15 (+n*16 -> +n*1024); k-chunk c, half h
#pragma unroll
  for (int c = 0; c < 2; ++c)
#pragma unroll
    for (int h = 0; h < 2; ++h) {
      int jq = c * 4 + 2 * h + (g >> 1);
      ysb[c][h] = (lane & 15) * 64 + ((jq ^ (lane & 7)) << 3) + (g & 1) * 4;
    }

  f32x4 oacc0[8], oacc1[8];  // [n], rows m=0 / m=1
#pragma unroll
  for (int n = 0; n < 8; ++n) { oacc0[n] = (f32x4){}; oacc1[n] = (f32x4){}; }

  for (int t = 0; t < nt; ++t) {
    wait_vm0();
    __syncthreads();
    const int cur = (t + 1) & 1, nxt = t & 1;
    if (t + 1 < nt) {
      const int j1 = jbeg + (t + 1) * 64;
#pragma unroll
      for (int q = 0; q < 4; ++q) {
        int c = wv * 4 + q;
        int lr = c * 4 + g;
        int gsrc = (lane & 15) ^ (lr & 7);
        gload16(&xbb[(j1 + lr) * 128 + gsrc * 8], &XjB[nxt][c * 512]);
      }
#pragma unroll
      for (int q = 0; q < 4; ++q) {
        int c = wv * 4 + q;
        int dr = c * 8 + (lane >> 3);
        int gsrc = (lane & 7) ^ (dr & 7);
        gload16(&ytb[(size_t)dr * NN + j1 + gsrc * 8], &YsB[nxt][c * 512]);
      }
    }
    const unsigned short* Xj = XjB[cur];
    const unsigned short* Ys = YsB[cur];

    // S^T: a{ni}[mj], C row = j = mj*16 + g*4 + r, col(lane&15) = i
    f32x4 s0[4], s1[4];
#pragma unroll
    for (int mj = 0; mj < 4; ++mj) { s0[mj] = (f32x4){}; s1[mj] = (f32x4){}; }
    __builtin_amdgcn_s_setprio(1);
#pragma unroll
    for (int kk = 0; kk < 4; ++kk) {
      bf16x8 ar0 = *(const bf16x8*)&Xj[xjb[kk]];
      bf16x8 ar1 = *(const bf16x8*)&Xj[xjb[kk] + 1 * 2048];
      bf16x8 ar2 = *(const bf16x8*)&Xj[xjb[kk] + 2 * 2048];
      bf16x8 ar3 = *(const bf16x8*)&Xj[xjb[kk] + 3 * 2048];
      s0[0] = __builtin_amdgcn_mfma_f32_16x16x32_bf16(ar0, bfr[0][kk], s0[0], 0, 0, 0);
      s1[0] = __builtin_amdgcn_mfma_f32_16x16x32_bf16(ar0, bfr[1][kk], s1[0], 0, 0, 0);
      s0[1] = __builtin_amdgcn_mfma_f32_16x16x32_bf16(ar1, bfr[0][kk], s0[1], 0, 0, 0);
      s1[1] = __builtin_amdgcn_mfma_f32_16x16x32_bf16(ar1, bfr[1][kk], s1[1], 0, 0, 0);
      s0[2] = __builtin_amdgcn_mfma_f32_16x16x32_bf16(ar2, bfr[0][kk], s0[2], 0, 0, 0);
      s1[2] = __builtin_amdgcn_mfma_f32_16x16x32_bf16(ar2, bfr[1][kk], s1[2], 0, 0, 0);
      s0[3] = __builtin_amdgcn_mfma_f32_16x16x32_bf16(ar3, bfr[0][kk], s0[3], 0, 0, 0);
      s1[3] = __builtin_amdgcn_mfma_f32_16x16x32_bf16(ar3, bfr[1][kk], s1[3], 0, 0, 0);
    }
    __builtin_amdgcn_s_setprio(0);
    // relu+pack: p{c}{ni}, k-chunk c covers j = c*32..c*32+31 (mj 2c, 2c+1)
    pk8 p00, p01, p10, p11;  // pCN: chunk C, ni N
    p00.u[0] = pkrelu(s0[0][0], s0[0][1]); p00.u[1] = pkrelu(s0[0][2], s0[0][3]);
    p00.u[2] = pkrelu(s0[1][0], s0[1][1]); p00.u[3] = pkrelu(s0[1][2], s0[1][3]);
    p01.u[0] = pkrelu(s1[0][0], s1[0][1]); p01.u[1] = pkrelu(s1[0][2], s1[0][3]);
    p01.u[2] = pkrelu(s1[1][0], s1[1][1]); p01.u[3] = pkrelu(s1[1][2], s1[1][3]);
    p10.u[0] = pkrelu(s0[2][0], s0[2][1]); p10.u[1] = pkrelu(s0[2][2], s0[2][3]);
    p10.u[2] = pkrelu(s0[3][0], s0[3][1]); p10.u[3] = pkrelu(s0[3][2], s0[3][3]);
    p11.u[0] = pkrelu(s1[2][0], s1[2][1]); p11.u[1] = pkrelu(s1[2][2], s1[2][3]);
    p11.u[2] = pkrelu(s1[3][0], s1[3][1]); p11.u[3] = pkrelu(s1[3][2], s1[3][3]);
    __builtin_amdgcn_s_setprio(1);
#pragma unroll
    for (int n = 0; n < 8; ++n) {
      pk8 bb0, bb1;
      bb0.u2[0] = *(const uint2*)&Ys[ysb[0][0] + n * 1024];
      bb0.u2[1] = *(const uint2*)&Ys[ysb[0][1] + n * 1024];
      bb1.u2[0] = *(const uint2*)&Ys[ysb[1][0] + n * 1024];
      bb1.u2[1] = *(const uint2*)&Ys[ysb[1][1] + n * 1024];
      oacc0[n] = __builtin_amdgcn_mfma_f32_16x16x32_bf16(p00.v, bb0.v, oacc0[n], 0, 0, 0);
      oacc1[n] = __builtin_amdgcn_mfma_f32_16x16x32_bf16(p01.v, bb0.v, oacc1[n], 0, 0, 0);
      oacc0[n] = __builtin_amdgcn_mfma_f32_16x16x32_bf16(p10.v, bb1.v, oacc0[n], 0, 0, 0);
      oacc1[n] = __builtin_amdgcn_mfma_f32_16x16x32_bf16(p11.v, bb1.v, oacc1[n], 0, 0, 0);
    }
    __builtin_amdgcn_s_setprio(0);
  }

  // epilogue: oacc -> bf16 via LDS (XjB contiguous 32 KB), coalesced store
  __syncthreads();
  unsigned short* sb = &XjB[0][0];  // 128 x 128 bf16
#pragma unroll
  for (int m = 0; m < 2; ++m)
#pragma unroll
    for (int n = 0; n < 8; ++n)
#pragma unroll
      for (int r = 0; r < 4; ++r) {
        int row = wv * 32 + m * 16 + g * 4 + r;
        int col = n * 16 + (lane & 15);
        sb[row * 128 + col] = f2bf(m == 0 ? oacc0[n][r] : oacc1[n][r]);
      }
  __syncthreads();
  for (int c = tid; c < 2048; c += 256) {
    int row = c >> 4, gq = c & 15;
    *(uint4*)&opart[((size_t)zc * (BN * NN) + b * NN + i0 + row) * DD + gq * 8] =
        *(const uint4*)&sb[row * 128 + gq * 8];
  }
}

// ---- kernel 5: out = tanh((sum_zc opart) @ W^T + bias) + x ----
__global__ __launch_bounds__(256) void k_final(const unsigned short* __restrict__ opart,
                                               int jc,
                                               const float* __restrict__ W,
                                               const float* __restrict__ bias,
                                               const float* __restrict__ x,
                                               float* __restrict__ out) {
  __shared__ float Wt[128 * 128];
  __shared__ unsigned short PreS[64 * 128];
  const int tid = threadIdx.x;
  const int r0 = blockIdx.x * 64;
  {
    int h = tid >> 1, k0 = (tid & 1) * 64;
    const float* wr = W + h * 128 + k0;
#pragma unroll
    for (int q = 0; q < 16; ++q) {
      float4 v = *(const float4*)(wr + q * 4);
      Wt[(k0 + q * 4 + 0) * 128 + h] = v.x;
      Wt[(k0 + q * 4 + 1) * 128 + h] = v.y;
      Wt[(k0 + q * 4 + 2) * 128 + h] = v.z;
      Wt[(k0 + q * 4 + 3) * 128 + h] = v.w;
    }
  }
  for (int c = tid; c < 1024; c += 256) {
    int row = c >> 4, gq = c & 15;
    float s[8] = {0.f, 0.f, 0.f, 0.f, 0.f, 0.f, 0.f, 0.f};
    for (int ch = 0; ch < jc; ++ch) {
      uint4 pk = *(const uint4*)&opart[((size_t)ch * (BN * NN) + r0 + row) * DD + gq * 8];
      alignas(16) unsigned short us[8];
      *(uint4*)us = pk;
#pragma unroll
      for (int u = 0; u < 8; ++u) s[u] += bf2f(us[u]);
    }
    alignas(16) unsigned short rs[8];
#pragma unroll
    for (int u = 0; u < 8; ++u) rs[u] = f2bf(s[u]);
    *(uint4*)&PreS[row * 128 + gq * 8] = *(const uint4*)rs;
  }
  const int h = tid & 127;
  float bh = bias[h];
  __syncthreads();
  for (int it = 0; it < 32; ++it) {
    int lr = it * 2 + (tid >> 7);
    int ri = r0 + lr;
    float acc = bh;
#pragma unroll
    for (int k8 = 0; k8 < 16; ++k8) {
      uint4 pk = *(const uint4*)&PreS[lr * 128 + k8 * 8];
      alignas(16) unsigned short us[8];
      *(uint4*)us = pk;
#pragma unroll
      for (int u = 0; u < 8; ++u) acc += bf2f(us[u]) * Wt[(k8 * 8 + u) * 128 + h];
    }
    out[(size_t)ri * 128 + h] = tanhf(acc) + x[(size_t)ri * 128 + h];
  }
}

extern "C" void kernel_launch(void* const* d_in, const int* in_sizes, int n_in,
                              void* d_out, int out_size, void* d_ws, size_t ws_size,
                              hipStream_t stream) {
  (void)in_sizes; (void)n_in; (void)out_size;
  const float* x = (const float*)d_in[0];
  const float* W = (const float*)d_in[1];
  const float* bias = (const float*)d_in[2];
  float* out = (float*)d_out;
  char* ws = (char*)d_ws;
  unsigned short* xb = (unsigned short*)ws;                       // 4 MB @ 0
  unsigned short* yt = (unsigned short*)(ws + (4u << 20));        // 4 MB @ 4M
  float* colpart = (float*)(ws + (8u << 20));                     // 512 KB @ 8M
  unsigned short* opart = (unsigned short*)(ws + (9u << 20));     // jc*4 MB @ 9M

  // jc=4: pass2 grid = 32*4*4 = 512 = exactly 2 blocks/CU (64 KB LDS)
  const size_t need4 = (9u << 20) + 4u * (4u << 20);
  const int jc = (ws_size >= need4) ? 4 : 1;

  k_cvt<<<1024, 256, 0, stream>>>(x, xb);
  k_colsum<<<dim3(32, 4, 8), 256, 0, stream>>>(xb, colpart);
  k_ytrans<<<dim3(2, 64, 4), 256, 0, stream>>>(x, colpart, yt);
  k_pass2<<<dim3(32, 4, jc), 256, 0, stream>>>(xb, yt, opart, jc);
  k_final<<<256, 256, 0, stream>>>(opart, jc, W, bias, x, out);
}

// Round 10
// 83.703 us; speedup vs baseline: 3.3744x; 1.3563x over previous
//
#include <hip/hip_runtime.h>
#include <hip/hip_bf16.h>

#define BN 4
#define NN 4096
#define DD 128

typedef __attribute__((ext_vector_type(8))) __bf16 bf16x8;
typedef __attribute__((ext_vector_type(4))) float f32x4;

typedef union {
  bf16x8 v;
  unsigned int u[4];
  uint2 u2[2];
} pk8;

typedef __attribute__((address_space(1))) const unsigned int* gas_p;
typedef __attribute__((address_space(3))) unsigned int* las_p;

__device__ __forceinline__ void gload16(const void* g, void* l) {
  __builtin_amdgcn_global_load_lds((gas_p)g, (las_p)l, 16, 0, 0);
}
__device__ __forceinline__ void wait_vm0() {
  asm volatile("s_waitcnt vmcnt(0)" ::: "memory");
}
__device__ __forceinline__ unsigned int cvtpk(float lo, float hi) {
  unsigned int r;
  asm("v_cvt_pk_bf16_f32 %0, %1, %2" : "=v"(r) : "v"(lo), "v"(hi));
  return r;
}
__device__ __forceinline__ unsigned int pkrelu(float lo, float hi) {
  return cvtpk(fmaxf(lo, 0.f), fmaxf(hi, 0.f));
}

__device__ inline unsigned short f2bf(float f) {
  unsigned int u = __float_as_uint(f);
  unsigned int r = (u + 0x7FFFu + ((u >> 16) & 1u)) >> 16;
  return (unsigned short)r;
}
__device__ inline float bf2f(unsigned short s) {
  return __uint_as_float(((unsigned int)s) << 16);
}

// ---------------- kernel 1: cast x (fp32) -> xb (bf16) ----------------
__global__ __launch_bounds__(256) void k_cvt(const float* __restrict__ x,
                                             unsigned short* __restrict__ xb) {
  int i = (blockIdx.x * 256 + threadIdx.x) * 8;
  float4 a = *(const float4*)(x + i);
  float4 c = *(const float4*)(x + i + 4);
  uint4 o;
  o.x = cvtpk(a.x, a.y);
  o.y = cvtpk(a.z, a.w);
  o.z = cvtpk(c.x, c.y);
  o.w = cvtpk(c.z, c.w);
  *(uint4*)(xb + i) = o;
}

// ---- kernel 2: colpart[(ic*BN+b)][j] = sum_{i in chunk ic} relu(<x_i,x_j>) ----
__global__ __launch_bounds__(256, 4) void k_colsum(const unsigned short* __restrict__ xb,
                                                   float* __restrict__ colpart) {
  __shared__ unsigned short XiB[2][64 * 128];  // 32 KB
  const int b = blockIdx.y, j0 = blockIdx.x * 128, ic = blockIdx.z;
  const int tid = threadIdx.x, lane = tid & 63, wv = tid >> 6;
  const unsigned short* xbb = xb + b * NN * DD;
  const int g = lane >> 4;
  const int ibeg = ic * (NN / 8);
  const int nt = (NN / 8) / 64;  // 8

#pragma unroll
  for (int hb = 0; hb < 2; ++hb)
#pragma unroll
    for (int q = 0; q < 4; ++q) {
      int c = wv * 4 + q;
      int lr = c * 4 + g;
      int gsrc = (lane & 15) ^ (lr & 7);
      gload16(&xbb[(j0 + hb * 64 + lr) * 128 + gsrc * 8], &XiB[hb][c * 512]);
    }
  wait_vm0();
  __syncthreads();

  bf16x8 bfr[2][4];
#pragma unroll
  for (int ni = 0; ni < 2; ++ni)
#pragma unroll
    for (int kk = 0; kk < 4; ++kk) {
      int lr = (wv & 1) * 32 + ni * 16 + (lane & 15);
      bfr[ni][kk] = *(const bf16x8*)&XiB[wv >> 1][lr * 128 + (((kk * 4 + g) ^ (lr & 7)) << 3)];
    }
  __syncthreads();

#pragma unroll
  for (int q = 0; q < 4; ++q) {
    int c = wv * 4 + q;
    int lr = c * 4 + g;
    int gsrc = (lane & 15) ^ (lr & 7);
    gload16(&xbb[(ibeg + lr) * 128 + gsrc * 8], &XiB[1][c * 512]);
  }

  int basek[4];
#pragma unroll
  for (int kk = 0; kk < 4; ++kk)
    basek[kk] = (lane & 15) * 128 + (((kk * 4 + g) ^ (lane & 7)) << 3);

  float colacc0 = 0.f, colacc1 = 0.f;
  for (int t = 0; t < nt; ++t) {
    wait_vm0();
    __syncthreads();
    const int cur = (t + 1) & 1, nxt = t & 1;
    if (t + 1 < nt) {
      const int i1 = ibeg + (t + 1) * 64;
#pragma unroll
      for (int q = 0; q < 4; ++q) {
        int c = wv * 4 + q;
        int lr = c * 4 + g;
        int gsrc = (lane & 15) ^ (lr & 7);
        gload16(&xbb[(i1 + lr) * 128 + gsrc * 8], &XiB[nxt][c * 512]);
      }
    }
    f32x4 a0[4], a1[4];
#pragma unroll
    for (int mj = 0; mj < 4; ++mj) { a0[mj] = (f32x4){}; a1[mj] = (f32x4){}; }
    __builtin_amdgcn_s_setprio(1);
#pragma unroll
    for (int kk = 0; kk < 4; ++kk) {
      bf16x8 ar0 = *(const bf16x8*)&XiB[cur][basek[kk]];
      bf16x8 ar1 = *(const bf16x8*)&XiB[cur][basek[kk] + 1 * 2048];
      bf16x8 ar2 = *(const bf16x8*)&XiB[cur][basek[kk] + 2 * 2048];
      bf16x8 ar3 = *(const bf16x8*)&XiB[cur][basek[kk] + 3 * 2048];
      a0[0] = __builtin_amdgcn_mfma_f32_16x16x32_bf16(ar0, bfr[0][kk], a0[0], 0, 0, 0);
      a1[0] = __builtin_amdgcn_mfma_f32_16x16x32_bf16(ar0, bfr[1][kk], a1[0], 0, 0, 0);
      a0[1] = __builtin_amdgcn_mfma_f32_16x16x32_bf16(ar1, bfr[0][kk], a0[1], 0, 0, 0);
      a1[1] = __builtin_amdgcn_mfma_f32_16x16x32_bf16(ar1, bfr[1][kk], a1[1], 0, 0, 0);
      a0[2] = __builtin_amdgcn_mfma_f32_16x16x32_bf16(ar2, bfr[0][kk], a0[2], 0, 0, 0);
      a1[2] = __builtin_amdgcn_mfma_f32_16x16x32_bf16(ar2, bfr[1][kk], a1[2], 0, 0, 0);
      a0[3] = __builtin_amdgcn_mfma_f32_16x16x32_bf16(ar3, bfr[0][kk], a0[3], 0, 0, 0);
      a1[3] = __builtin_amdgcn_mfma_f32_16x16x32_bf16(ar3, bfr[1][kk], a1[3], 0, 0, 0);
    }
    __builtin_amdgcn_s_setprio(0);
    {
      float s0 = 0.f, s1 = 0.f;
#pragma unroll
      for (int mj = 0; mj < 4; ++mj)
#pragma unroll
        for (int r = 0; r < 4; ++r) {
          s0 += fmaxf(a0[mj][r], 0.f);
          s1 += fmaxf(a1[mj][r], 0.f);
        }
      s0 += __shfl_xor(s0, 16); s0 += __shfl_xor(s0, 32);
      s1 += __shfl_xor(s1, 16); s1 += __shfl_xor(s1, 32);
      colacc0 += s0; colacc1 += s1;
    }
  }
  if (lane < 16) {
    colpart[(ic * BN + b) * NN + j0 + wv * 32 + lane] = colacc0;
    colpart[(ic * BN + b) * NN + j0 + wv * 32 + 16 + lane] = colacc1;
  }
}

// ---- kernel 3: yt[b][d][j] = bf16(x[b][j][d] / sum_ic colpart) ----
__global__ __launch_bounds__(256) void k_ytrans(const float* __restrict__ x,
                                                const float* __restrict__ colpart,
                                                unsigned short* __restrict__ yt) {
  __shared__ unsigned short T[64 * 72];
  const int b = blockIdx.z, j0 = blockIdx.y * 64, d0 = blockIdx.x * 64;
  const int tid = threadIdx.x;
  int jr = tid >> 2, q0 = (tid & 3) * 16;
  float cs = 0.f;
#pragma unroll
  for (int ic = 0; ic < 8; ++ic) cs += colpart[(ic * BN + b) * NN + j0 + jr];
  float inv = 1.0f / cs;
  const float* xr = x + (size_t)(b * NN + j0 + jr) * DD + d0 + q0;
#pragma unroll
  for (int q = 0; q < 4; ++q) {
    float4 v = *(const float4*)(xr + q * 4);
    int dc = q0 + q * 4;
    T[jr * 72 + dc + 0] = f2bf(v.x * inv);
    T[jr * 72 + dc + 1] = f2bf(v.y * inv);
    T[jr * 72 + dc + 2] = f2bf(v.z * inv);
    T[jr * 72 + dc + 3] = f2bf(v.w * inv);
  }
  __syncthreads();
  for (int c = tid; c < 512; c += 256) {
    int dr = c >> 3, jg = c & 7;
    alignas(16) unsigned short tmp[8];
#pragma unroll
    for (int u = 0; u < 8; ++u) tmp[u] = T[(jg * 8 + u) * 72 + dr];
    *(uint4*)&yt[(size_t)(b * DD + d0 + dr) * NN + j0 + jg * 8] = *(const uint4*)tmp;
  }
}

// ---- kernel 4: opart[zc][b*NN+i][:] = sum_{j in chunk zc} relu(<x_i,x_j>) y[j][:] ----
__global__ __launch_bounds__(256, 2) void k_pass2(const unsigned short* __restrict__ xb,
                                                  const unsigned short* __restrict__ yt,
                                                  unsigned short* __restrict__ opart,
                                                  int jc) {
  __shared__ unsigned short XjB[2][64 * 128];
  __shared__ unsigned short YsB[2][128 * 64];
  const int b = blockIdx.y, i0 = blockIdx.x * 128, zc = blockIdx.z;
  const int tid = threadIdx.x, lane = tid & 63, wv = tid >> 6;
  const unsigned short* xbb = xb + b * NN * DD;
  const unsigned short* ytb = yt + (size_t)b * DD * NN;
  const int g = lane >> 4;

  const int jspan = NN / jc;
  const int jbeg = zc * jspan;
  const int nt = jspan / 64;

#pragma unroll
  for (int hb = 0; hb < 2; ++hb)
#pragma unroll
    for (int q = 0; q < 4; ++q) {
      int c = wv * 4 + q;
      int lr = c * 4 + g;
      int gsrc = (lane & 15) ^ (lr & 7);
      gload16(&xbb[(i0 + hb * 64 + lr) * 128 + gsrc * 8], &XjB[hb][c * 512]);
    }
#pragma unroll
  for (int q = 0; q < 4; ++q) {
    int c = wv * 4 + q;
    int dr = c * 8 + (lane >> 3);
    int gsrc = (lane & 7) ^ (dr & 7);
    gload16(&ytb[(size_t)dr * NN + jbeg + gsrc * 8], &YsB[1][c * 512]);
  }
  wait_vm0();
  __syncthreads();

  bf16x8 bfr[2][4];
#pragma unroll
  for (int ni = 0; ni < 2; ++ni)
#pragma unroll
    for (int kk = 0; kk < 4; ++kk) {
      int lr = (wv & 1) * 32 + ni * 16 + (lane & 15);
      bfr[ni][kk] = *(const bf16x8*)&XjB[wv >> 1][lr * 128 + (((kk * 4 + g) ^ (lr & 7)) << 3)];
    }
  __syncthreads();

#pragma unroll
  for (int q = 0; q < 4; ++q) {
    int c = wv * 4 + q;
    int lr = c * 4 + g;
    int gsrc = (lane & 15) ^ (lr & 7);
    gload16(&xbb[(jbeg + lr) * 128 + gsrc * 8], &XjB[1][c * 512]);
  }

  int xjb[4];
#pragma unroll
  for (int kk = 0; kk < 4; ++kk)
    xjb[kk] = (lane & 15) * 128 + (((kk * 4 + g) ^ (lane & 7)) << 3);
  int ysb[2][2];
#pragma unroll
  for (int c = 0; c < 2; ++c)
#pragma unroll
    for (int h = 0; h < 2; ++h) {
      int jq = c * 4 + 2 * h + (g >> 1);
      ysb[c][h] = (lane & 15) * 64 + ((jq ^ (lane & 7)) << 3) + (g & 1) * 4;
    }

  f32x4 oacc0[8], oacc1[8];
#pragma unroll
  for (int n = 0; n < 8; ++n) { oacc0[n] = (f32x4){}; oacc1[n] = (f32x4){}; }

  for (int t = 0; t < nt; ++t) {
    wait_vm0();
    __syncthreads();
    const int cur = (t + 1) & 1, nxt = t & 1;
    if (t + 1 < nt) {
      const int j1 = jbeg + (t + 1) * 64;
#pragma unroll
      for (int q = 0; q < 4; ++q) {
        int c = wv * 4 + q;
        int lr = c * 4 + g;
        int gsrc = (lane & 15) ^ (lr & 7);
        gload16(&xbb[(j1 + lr) * 128 + gsrc * 8], &XjB[nxt][c * 512]);
      }
#pragma unroll
      for (int q = 0; q < 4; ++q) {
        int c = wv * 4 + q;
        int dr = c * 8 + (lane >> 3);
        int gsrc = (lane & 7) ^ (dr & 7);
        gload16(&ytb[(size_t)dr * NN + j1 + gsrc * 8], &YsB[nxt][c * 512]);
      }
    }
    const unsigned short* Xj = XjB[cur];
    const unsigned short* Ys = YsB[cur];

    f32x4 s0[4], s1[4];
#pragma unroll
    for (int mj = 0; mj < 4; ++mj) { s0[mj] = (f32x4){}; s1[mj] = (f32x4){}; }
    __builtin_amdgcn_s_setprio(1);
#pragma unroll
    for (int kk = 0; kk < 4; ++kk) {
      bf16x8 ar0 = *(const bf16x8*)&Xj[xjb[kk]];
      bf16x8 ar1 = *(const bf16x8*)&Xj[xjb[kk] + 1 * 2048];
      bf16x8 ar2 = *(const bf16x8*)&Xj[xjb[kk] + 2 * 2048];
      bf16x8 ar3 = *(const bf16x8*)&Xj[xjb[kk] + 3 * 2048];
      s0[0] = __builtin_amdgcn_mfma_f32_16x16x32_bf16(ar0, bfr[0][kk], s0[0], 0, 0, 0);
      s1[0] = __builtin_amdgcn_mfma_f32_16x16x32_bf16(ar0, bfr[1][kk], s1[0], 0, 0, 0);
      s0[1] = __builtin_amdgcn_mfma_f32_16x16x32_bf16(ar1, bfr[0][kk], s0[1], 0, 0, 0);
      s1[1] = __builtin_amdgcn_mfma_f32_16x16x32_bf16(ar1, bfr[1][kk], s1[1], 0, 0, 0);
      s0[2] = __builtin_amdgcn_mfma_f32_16x16x32_bf16(ar2, bfr[0][kk], s0[2], 0, 0, 0);
      s1[2] = __builtin_amdgcn_mfma_f32_16x16x32_bf16(ar2, bfr[1][kk], s1[2], 0, 0, 0);
      s0[3] = __builtin_amdgcn_mfma_f32_16x16x32_bf16(ar3, bfr[0][kk], s0[3], 0, 0, 0);
      s1[3] = __builtin_amdgcn_mfma_f32_16x16x32_bf16(ar3, bfr[1][kk], s1[3], 0, 0, 0);
    }
    __builtin_amdgcn_s_setprio(0);
    pk8 p00, p01, p10, p11;
    p00.u[0] = pkrelu(s0[0][0], s0[0][1]); p00.u[1] = pkrelu(s0[0][2], s0[0][3]);
    p00.u[2] = pkrelu(s0[1][0], s0[1][1]); p00.u[3] = pkrelu(s0[1][2], s0[1][3]);
    p01.u[0] = pkrelu(s1[0][0], s1[0][1]); p01.u[1] = pkrelu(s1[0][2], s1[0][3]);
    p01.u[2] = pkrelu(s1[1][0], s1[1][1]); p01.u[3] = pkrelu(s1[1][2], s1[1][3]);
    p10.u[0] = pkrelu(s0[2][0], s0[2][1]); p10.u[1] = pkrelu(s0[2][2], s0[2][3]);
    p10.u[2] = pkrelu(s0[3][0], s0[3][1]); p10.u[3] = pkrelu(s0[3][2], s0[3][3]);
    p11.u[0] = pkrelu(s1[2][0], s1[2][1]); p11.u[1] = pkrelu(s1[2][2], s1[2][3]);
    p11.u[2] = pkrelu(s1[3][0], s1[3][1]); p11.u[3] = pkrelu(s1[3][2], s1[3][3]);
    __builtin_amdgcn_s_setprio(1);
#pragma unroll
    for (int n = 0; n < 8; ++n) {
      pk8 bb0, bb1;
      bb0.u2[0] = *(const uint2*)&Ys[ysb[0][0] + n * 1024];
      bb0.u2[1] = *(const uint2*)&Ys[ysb[0][1] + n * 1024];
      bb1.u2[0] = *(const uint2*)&Ys[ysb[1][0] + n * 1024];
      bb1.u2[1] = *(const uint2*)&Ys[ysb[1][1] + n * 1024];
      oacc0[n] = __builtin_amdgcn_mfma_f32_16x16x32_bf16(p00.v, bb0.v, oacc0[n], 0, 0, 0);
      oacc1[n] = __builtin_amdgcn_mfma_f32_16x16x32_bf16(p01.v, bb0.v, oacc1[n], 0, 0, 0);
      oacc0[n] = __builtin_amdgcn_mfma_f32_16x16x32_bf16(p10.v, bb1.v, oacc0[n], 0, 0, 0);
      oacc1[n] = __builtin_amdgcn_mfma_f32_16x16x32_bf16(p11.v, bb1.v, oacc1[n], 0, 0, 0);
    }
    __builtin_amdgcn_s_setprio(0);
  }

  __syncthreads();
  unsigned short* sb = &XjB[0][0];
#pragma unroll
  for (int m = 0; m < 2; ++m)
#pragma unroll
    for (int n = 0; n < 8; ++n)
#pragma unroll
      for (int r = 0; r < 4; ++r) {
        int row = wv * 32 + m * 16 + g * 4 + r;
        int col = n * 16 + (lane & 15);
        sb[row * 128 + col] = f2bf(m == 0 ? oacc0[n][r] : oacc1[n][r]);
      }
  __syncthreads();
  for (int c = tid; c < 2048; c += 256) {
    int row = c >> 4, gq = c & 15;
    *(uint4*)&opart[((size_t)zc * (BN * NN) + b * NN + i0 + row) * DD + gq * 8] =
        *(const uint4*)&sb[row * 128 + gq * 8];
  }
}

// ---- kernel 5 (MFMA): out = tanh((sum_zc opart) @ W^T + bias) + x ----
// 512 blocks x 32 rows. W staged once as swizzled bf16; PreS = summed opart.
// Wave wv owns h-cols wv*32..+31; 2 row-blocks x 2 h-blocks x k=128 = 16 MFMA.
__global__ __launch_bounds__(256) void k_final(const unsigned short* __restrict__ opart,
                                               int jc,
                                               const float* __restrict__ W,
                                               const float* __restrict__ bias,
                                               const float* __restrict__ x,
                                               float* __restrict__ out) {
  __shared__ unsigned short Wb[128 * 128];    // 32 KB bf16, swizzled
  __shared__ unsigned short PreS[32 * 128];   // 8 KB bf16, swizzled
  const int tid = threadIdx.x, lane = tid & 63, wv = tid >> 6;
  const int g = lane >> 4;
  const int r0 = blockIdx.x * 32;

  // stage W -> bf16 swizzled: thread covers row h = tid>>1, half k0 = (tid&1)*64
  {
    int h = tid >> 1, k0h = (tid & 1) * 8;  // granule base
    const float* wr = W + h * 128 + k0h * 8;
#pragma unroll
    for (int q = 0; q < 8; ++q) {
      float4 v0 = *(const float4*)(wr + q * 8);
      float4 v1 = *(const float4*)(wr + q * 8 + 4);
      uint4 o;
      o.x = cvtpk(v0.x, v0.y); o.y = cvtpk(v0.z, v0.w);
      o.z = cvtpk(v1.x, v1.y); o.w = cvtpk(v1.z, v1.w);
      int gq = k0h + q;
      *(uint4*)&Wb[h * 128 + ((gq ^ (h & 7)) << 3)] = o;
    }
  }
  // stage PreS = sum_ch opart (bf16 add in f32), swizzled
  for (int c = tid; c < 512; c += 256) {
    int row = c >> 4, gq = c & 15;
    float s[8] = {0.f, 0.f, 0.f, 0.f, 0.f, 0.f, 0.f, 0.f};
    for (int ch = 0; ch < jc; ++ch) {
      uint4 pk = *(const uint4*)&opart[((size_t)ch * (BN * NN) + r0 + row) * DD + gq * 8];
      alignas(16) unsigned short us[8];
      *(uint4*)us = pk;
#pragma unroll
      for (int u = 0; u < 8; ++u) s[u] += bf2f(us[u]);
    }
    uint4 o;
    o.x = cvtpk(s[0], s[1]); o.y = cvtpk(s[2], s[3]);
    o.z = cvtpk(s[4], s[5]); o.w = cvtpk(s[6], s[7]);
    *(uint4*)&PreS[row * 128 + ((gq ^ (row & 7)) << 3)] = o;
  }
  __syncthreads();

  // A-frags (pre rows), B-frags (W cols this wave)
  bf16x8 af[2][4], bf[2][4];
#pragma unroll
  for (int m = 0; m < 2; ++m)
#pragma unroll
    for (int kk = 0; kk < 4; ++kk) {
      int row = m * 16 + (lane & 15);
      af[m][kk] = *(const bf16x8*)&PreS[row * 128 + (((kk * 4 + g) ^ (row & 7)) << 3)];
    }
#pragma unroll
  for (int n = 0; n < 2; ++n)
#pragma unroll
    for (int kk = 0; kk < 4; ++kk) {
      int h = wv * 32 + n * 16 + (lane & 15);
      bf[n][kk] = *(const bf16x8*)&Wb[h * 128 + (((kk * 4 + g) ^ (h & 7)) << 3)];
    }

  f32x4 acc[2][2] = {};
#pragma unroll
  for (int kk = 0; kk < 4; ++kk) {
    acc[0][0] = __builtin_amdgcn_mfma_f32_16x16x32_bf16(af[0][kk], bf[0][kk], acc[0][0], 0, 0, 0);
    acc[0][1] = __builtin_amdgcn_mfma_f32_16x16x32_bf16(af[0][kk], bf[1][kk], acc[0][1], 0, 0, 0);
    acc[1][0] = __builtin_amdgcn_mfma_f32_16x16x32_bf16(af[1][kk], bf[0][kk], acc[1][0], 0, 0, 0);
    acc[1][1] = __builtin_amdgcn_mfma_f32_16x16x32_bf16(af[1][kk], bf[1][kk], acc[1][1], 0, 0, 0);
  }

  float bh0 = bias[wv * 32 + (lane & 15)];
  float bh1 = bias[wv * 32 + 16 + (lane & 15)];
  // C layout: row (A index) = g*4 + r, col (B index) = lane&15
#pragma unroll
  for (int m = 0; m < 2; ++m)
#pragma unroll
    for (int n = 0; n < 2; ++n)
#pragma unroll
      for (int r = 0; r < 4; ++r) {
        int row = r0 + m * 16 + g * 4 + r;
        int h = wv * 32 + n * 16 + (lane & 15);
        size_t idx = (size_t)row * 128 + h;
        out[idx] = tanhf(acc[m][n][r] + (n == 0 ? bh0 : bh1)) + x[idx];
      }
}

extern "C" void kernel_launch(void* const* d_in, const int* in_sizes, int n_in,
                              void* d_out, int out_size, void* d_ws, size_t ws_size,
                              hipStream_t stream) {
  (void)in_sizes; (void)n_in; (void)out_size;
  const float* x = (const float*)d_in[0];
  const float* W = (const float*)d_in[1];
  const float* bias = (const float*)d_in[2];
  float* out = (float*)d_out;
  char* ws = (char*)d_ws;
  unsigned short* xb = (unsigned short*)ws;                       // 4 MB @ 0
  unsigned short* yt = (unsigned short*)(ws + (4u << 20));        // 4 MB @ 4M
  float* colpart = (float*)(ws + (8u << 20));                     // 512 KB @ 8M
  unsigned short* opart = (unsigned short*)(ws + (9u << 20));     // jc*4 MB @ 9M

  const size_t need4 = (9u << 20) + 4u * (4u << 20);
  const int jc = (ws_size >= need4) ? 4 : 1;

  k_cvt<<<1024, 256, 0, stream>>>(x, xb);
  k_colsum<<<dim3(32, 4, 8), 256, 0, stream>>>(xb, colpart);
  k_ytrans<<<dim3(2, 64, 4), 256, 0, stream>>>(x, colpart, yt);
  k_pass2<<<dim3(32, 4, jc), 256, 0, stream>>>(xb, yt, opart, jc);
  k_final<<<512, 256, 0, stream>>>(opart, jc, W, bias, x, out);
}